// Round 7
// baseline (2110.163 us; speedup 1.0000x reference)
//
#include <hip/hip_runtime.h>
#include <math.h>

#define Bn 64
#define Tn 128
#define TCn 512
#define CEn 64
#define CHn 256
#define TAGSn 50
#define DWPn 640   // word-LSTM input dim padded 612 -> 640

typedef float f32x4 __attribute__((ext_vector_type(4)));

__device__ __forceinline__ float sigf(float x){ return 1.0f/(1.0f+expf(-x)); }

// fast gate nonlinearities: v_exp_f32 + v_rcp_f32, endpoint-safe
__device__ __forceinline__ float fsig(float x){
  return __builtin_amdgcn_rcpf(1.f + exp2f(-1.4426950408889634f*x));
}
__device__ __forceinline__ float ftanh(float x){
  return 1.f - 2.f*__builtin_amdgcn_rcpf(1.f + exp2f(2.885390081777927f*x));
}

// float -> OCP e4m3fn (RNE, denormal-correct, saturating) — used in prep only
__device__ __forceinline__ unsigned f2e4m3(float x){
  unsigned s = (__float_as_uint(x) >> 24) & 0x80u;
  float ax = fabsf(x);
  if (ax < 0.015625f){
    int q = (int)rintf(ax * 512.f);
    if (q >= 8) return s | 0x08u;
    return s | (unsigned)q;
  }
  if (ax > 464.f) return s | 0x7eu;
  int e; float mfr = frexpf(ax, &e);
  int q = (int)rintf(mfr * 16.f);
  int E = e + 6;
  if (q == 16){ q = 8; E += 1; }
  if (E > 15 || (E == 15 && q == 15)) return s | 0x7eu;
  return s | (unsigned)((E<<3) | (q - 8));
}

// pack 4 floats -> 4 fp8 bytes via HW converter
__device__ __forceinline__ unsigned pk4_fp8(float a, float b, float c, float d){
  int r = __builtin_amdgcn_cvt_pk_fp8_f32(a, b, 0, false);
  r = __builtin_amdgcn_cvt_pk_fp8_f32(c, d, r, true);
  return (unsigned)r;
}

// ---------------------------------------------------------------------------
// CW[d][c][u*4+k] = b_d[k*256+u] + sum_e ceW[c][e]*Wih_d[k*256+u][e]
__global__ void k_prep_cw(const float* __restrict__ ceW,
                          const float* __restrict__ Wf, const float* __restrict__ bf,
                          const float* __restrict__ Wb, const float* __restrict__ bb,
                          float* __restrict__ CWf, float* __restrict__ CWb){
  const int c = blockIdx.x, u = threadIdx.x;
  const float* Wih  = blockIdx.y ? Wb : Wf;
  const float* bias = blockIdx.y ? bb : bf;
  float*       CW   = blockIdx.y ? CWb : CWf;
  __shared__ float ce[CEn];
  if (u < CEn) ce[u] = ceW[c*CEn + u];
  __syncthreads();
  float a[4];
  #pragma unroll
  for (int k=0;k<4;k++){
    const float* wr = Wih + (size_t)(k*CHn+u)*CEn;
    float s = bias[k*CHn+u];
    #pragma unroll 4
    for (int e=0;e<CEn;e++) s += ce[e]*wr[e];
    a[k]=s;
  }
  ((float4*)CW)[c*CHn+u] = make_float4(a[0],a[1],a[2],a[3]);
}

// fp8 e4m3 Whh. w<2 (char): gate-interleaved row permutation
//   out row r' = wv*64+nt*16+m  <-  src row nt*256 + wv*16 + m
// w>=2 (word): plain row order. grid (512,4) x 256.
__global__ void k_prep_w8(const float* __restrict__ W0, const float* __restrict__ W1,
                          const float* __restrict__ W2, const float* __restrict__ W3,
                          unsigned short* __restrict__ O0, unsigned short* __restrict__ O1,
                          unsigned short* __restrict__ O2, unsigned short* __restrict__ O3){
  const int w = blockIdx.y;
  const float* W = (w==0)?W0:(w==1)?W1:(w==2)?W2:W3;
  unsigned short* O = (w==0)?O0:(w==1)?O1:(w==2)?O2:O3;
  const int i = blockIdx.x*256 + threadIdx.x;      // 131072 pairs
  const int rp = i >> 7;                           // out row
  const int kp = (i & 127) * 2;                    // k pair base
  const int sr = (w < 2) ? ((((rp>>4)&3)*256) + ((rp>>6)*16) + (rp&15)) : rp;
  const float a = W[(size_t)sr*CHn + kp], b = W[(size_t)sr*CHn + kp + 1];
  O[(size_t)rp*128 + (kp>>1)] = (unsigned short)(f2e4m3(a) | (f2e4m3(b)<<8));
}

// pad word Wih (1024,612) -> (1024,640)
__global__ void k_pad(const float* __restrict__ Wf, const float* __restrict__ Wb,
                      float* __restrict__ Pf, float* __restrict__ Pb){
  const int j = blockIdx.x;
  const float* Win  = blockIdx.y ? Wb : Wf;
  float*       Wout = blockIdx.y ? Pb : Pf;
  for (int col=threadIdx.x; col<DWPn; col+=256)
    Wout[(size_t)j*DWPn+col] = (col<612) ? Win[(size_t)j*612+col] : 0.f;
}

// pad emW (50,512)->(64,512), emb (50)->(64)
__global__ void k_pad_em(const float* __restrict__ emW, const float* __restrict__ emb,
                         float* __restrict__ Wp, float* __restrict__ bp){
  const int j = blockIdx.x;
  for (int col=threadIdx.x; col<512; col+=256)
    Wp[(size_t)j*512+col] = (j<TAGSn) ? emW[(size_t)j*512+col] : 0.f;
  if (threadIdx.x==0) bp[j] = (j<TAGSn) ? emb[j] : 0.f;
}

// stable-compaction ranks from cmakers only; grid (64,2), 64 threads (1 wave)
__global__ void k_prep_pos(const float* __restrict__ cmf, const float* __restrict__ cmb,
                           int* __restrict__ pf, int* __restrict__ pb){
  const float* cm = blockIdx.y ? cmb : cmf;
  int* pos        = blockIdx.y ? pb : pf;
  const int n = blockIdx.x, lane = threadIdx.x;
  int base = 0;
  for (int c=0;c<TCn/64;c++){
    int t = c*64 + lane;
    bool m = cm[n*TCn+t] != 0.f;
    unsigned long long bal = __ballot(m);
    int before = __popcll(bal & ((1ULL<<lane)-1ULL));
    int r = base + before;
    pos[n*TCn+t] = (m && r < Tn) ? r : -1;
    base += __popcll(bal);
  }
}

// ---------------------------------------------------------------------------
// char LSTM via MFMA, gate-interleaved columns, M=16 seqs/block.
// 8 blocks = dir(2) x rowgroup(4). 1024 threads = 16 waves.
// Wave wv owns units [wv*16, wv*16+16) x 4 gates. After MFMA, lane (m,g)
// holds acc[gate][rg] = z_gate(row g*4+rg, unit wv*16+m) — gates in-register.
// h-exchange: pk4_fp8 + 4x4 byte transpose (shfl_xor+v_perm) + 1 dword write.
// ONE barrier per step.
__global__ __launch_bounds__(1024, 4)
void k_char_lstm(const int* __restrict__ cmf, const int* __restrict__ cmb,
                 const float* __restrict__ CWf, const float* __restrict__ CWb,
                 const unsigned char* __restrict__ W8f, const unsigned char* __restrict__ W8b,
                 const int* __restrict__ posf, const int* __restrict__ posb,
                 float* __restrict__ sub){
  const int dir = blockIdx.x >> 2, mg = blockIdx.x & 3;
  const int n0 = mg*16;
  const int t1 = threadIdx.x;
  const int wv = t1 >> 6, lane = t1 & 63;
  const int m = lane & 15, g = lane >> 4;
  const int*    cm  = dir ? cmb : cmf;
  const float4* CW  = (const float4*)(dir ? CWb : CWf);
  const unsigned char* W8 = dir ? W8b : W8f;
  const int*    pos = dir ? posb : posf;
  const int dofs = dir ? CHn : 0;

  // hbuf[par][row][unit] fp8 bytes, row stride 264 B (66 dwords)
  __shared__ unsigned hb[2][16][66];

  // B fragments (permuted W8): rows wv*64+nt*16+m, k = kt*32+g*8..+7
  long Bfr[4][8];
  #pragma unroll
  for (int nt=0;nt<4;nt++)
    #pragma unroll
    for (int kt=0;kt<8;kt++)
      Bfr[nt][kt] = *(const long*)(W8 + (size_t)(wv*64 + nt*16 + m)*256 + kt*32 + g*8);

  for (int j=t1; j<2*16*66; j+=1024) ((unsigned*)hb)[j] = 0u;

  const int uu = wv*16 + m;          // unit this lane owns in gate phase
  const int b4 = m & 3, a4 = m >> 2; // transpose sub-group coords
  float cst[4] = {0.f,0.f,0.f,0.f};
  int par = 0;
  __syncthreads();

  for (int t=0;t<TCn;t++){
    // per-row inputs (independent of h -> issued early, hidden under MFMA)
    int pp[4]; float4 cw[4];
    #pragma unroll
    for (int rg=0;rg<4;rg++){
      const int seq = n0 + g*4 + rg;
      const int ci = cm[seq*TCn + t];
      pp[rg] = pos[seq*TCn + t];
      cw[rg] = CW[(size_t)ci*CHn + uu];
    }
    // MFMA phase: A row m = hbuf row m, k = unit
    f32x4 acc[4];
    #pragma unroll
    for (int nt=0;nt<4;nt++){ acc[nt][0]=0.f; acc[nt][1]=0.f; acc[nt][2]=0.f; acc[nt][3]=0.f; }
    const char* hrow = (const char*)&hb[par][0][0] + m*264;
    #pragma unroll
    for (int kt=0;kt<8;kt++){
      const long afr = *(const long*)(hrow + kt*32 + g*8);
      #pragma unroll
      for (int nt=0;nt<4;nt++)
        acc[nt] = __builtin_amdgcn_mfma_f32_16x16x32_fp8_fp8(afr, Bfr[nt][kt], acc[nt], 0,0,0);
    }
    // gate phase: all in-register (acc[gate][rg])
    float hr[4];
    #pragma unroll
    for (int rg=0;rg<4;rg++){
      const float zi = acc[0][rg] + cw[rg].x;
      const float zf = acc[1][rg] + cw[rg].y;
      const float zg = acc[2][rg] + cw[rg].z;
      const float zo = acc[3][rg] + cw[rg].w;
      cst[rg] = fsig(zf)*cst[rg] + fsig(zi)*ftanh(zg);
      hr[rg] = fsig(zo)*ftanh(cst[rg]);
      if (pp[rg]>=0) sub[(size_t)((n0+g*4+rg)*Tn+pp[rg])*512 + dofs + uu] = hr[rg];
    }
    // pack + 4x4 byte transpose across lanes b4=0..3 (units 4*a4..+3)
    unsigned D = pk4_fp8(hr[0], hr[1], hr[2], hr[3]);
    unsigned tv = (unsigned)__shfl_xor((int)D, 1);
    D = (b4&1) ? __builtin_amdgcn_perm(D, tv, 0x07030501u)
               : __builtin_amdgcn_perm(D, tv, 0x02060004u);
    tv = (unsigned)__shfl_xor((int)D, 2);
    D = (b4&2) ? __builtin_amdgcn_perm(D, tv, 0x07060302u)
               : __builtin_amdgcn_perm(D, tv, 0x01000504u);
    // D = fp8 h of row g*4+b4, units wv*16+a4*4..+3
    hb[par^1][g*4+b4][wv*4+a4] = D;
    __syncthreads();
    par ^= 1;
  }
}

// ---------------------------------------------------------------------------
// word LSTM via MFMA (unchanged R6 structure): 64 blocks, M=4, plain W8.
__global__ __launch_bounds__(1024, 4)
void k_word_lstm(const float* __restrict__ wXf, const float* __restrict__ wXb,
                 const unsigned char* __restrict__ W8f, const unsigned char* __restrict__ W8b,
                 float* __restrict__ hout){
  const int dir = blockIdx.x >> 5, mg = blockIdx.x & 31;
  const int t0r = mg*4;
  const int t1 = threadIdx.x;
  const int wv = t1 >> 6, lane = t1 & 63;
  const int m = lane & 15, g = lane >> 4;
  const float* wX = dir ? wXb : wXf;
  const unsigned char* W8 = dir ? W8b : W8f;
  const int dofs = dir ? CHn : 0;

  __shared__ float zbuf[4][1040];
  __shared__ unsigned long hbufl[2][16][32];

  long Bfr[4][8];
  #pragma unroll
  for (int nt=0;nt<4;nt++)
    #pragma unroll
    for (int kt=0;kt<8;kt++)
      Bfr[nt][kt] = *(const long*)(W8 + (size_t)(wv*64 + nt*16 + m)*256 + kt*32 + g*8);

  ((unsigned long*)hbufl)[t1] = 0ul;
  const int u = t1 & 255, rw = t1 >> 8;
  float cst = 0.f;
  int par = 0;
  __syncthreads();

  for (int s=0;s<64;s++){
    const int n = dir ? (63-s) : s;
    const float* xp = wX + (size_t)(n*Tn + t0r + rw)*1024 + u;
    const float4 zin = make_float4(xp[0], xp[256], xp[512], xp[768]);
    f32x4 acc[4];
    #pragma unroll
    for (int nt=0;nt<4;nt++){ acc[nt][0]=0.f; acc[nt][1]=0.f; acc[nt][2]=0.f; acc[nt][3]=0.f; }
    #pragma unroll
    for (int kt=0;kt<8;kt++){
      const long afr = (long)hbufl[par][m][(kt*4+g)^m];
      #pragma unroll
      for (int nt=0;nt<4;nt++)
        acc[nt] = __builtin_amdgcn_mfma_f32_16x16x32_fp8_fp8(afr, Bfr[nt][kt], acc[nt], 0,0,0);
    }
    if (g==0){
      #pragma unroll
      for (int nt=0;nt<4;nt++){
        const int col = wv*64 + nt*16 + m;
        #pragma unroll
        for (int rg=0;rg<4;rg++)
          zbuf[rg][col] = acc[nt][rg];
      }
    }
    __syncthreads();
    {
      const float zi = zbuf[rw][u      ] + zin.x;
      const float zf = zbuf[rw][256+u  ] + zin.y;
      const float zg = zbuf[rw][512+u  ] + zin.z;
      const float zo = zbuf[rw][768+u  ] + zin.w;
      cst = fsig(zf)*cst + fsig(zi)*ftanh(zg);
      const float hn = fsig(zo)*ftanh(cst);
      ((unsigned char*)&hbufl[par^1][rw][0])[(((u>>3)^rw)<<3)|(u&7)] = (unsigned char)f2e4m3(hn);
      hout[(size_t)(n*Tn + t0r + rw)*512 + dofs + u] = hn;
    }
    __syncthreads();
    par ^= 1;
  }
}

// ---------------------------------------------------------------------------
// generic fp32 GEMM: C[m][n] = bias[n] + sum_k A[m][k]*W[n][k]
__global__ __launch_bounds__(256)
void k_gemm(const float* __restrict__ A, int lda, int K, int ldw,
            const float* __restrict__ W0, const float* __restrict__ W1,
            const float* __restrict__ b0, const float* __restrict__ b1,
            float* __restrict__ C0, float* __restrict__ C1, int ldc){
  const float* W    = blockIdx.z ? W1 : W0;
  const float* bias = blockIdx.z ? b1 : b0;
  float*       C    = blockIdx.z ? C1 : C0;
  const int m0 = blockIdx.x*128, n0 = blockIdx.y*64;
  __shared__ float As[32][132];
  __shared__ float Bs[32][68];
  const int tid = threadIdx.x;
  float acc[8][4];
  #pragma unroll
  for (int i=0;i<8;i++){
    #pragma unroll
    for (int j=0;j<4;j++) acc[i][j]=0.f;
  }
  const int tm = tid & 15, tn = tid >> 4;
  for (int kc=0; kc<K; kc+=32){
    #pragma unroll
    for (int it=0; it<4; it++){
      int fl = tid + it*256; int r = fl>>3; int kq = fl&7;
      float4 v = *(const float4*)(A + (size_t)(m0+r)*lda + kc + kq*4);
      As[kq*4+0][r]=v.x; As[kq*4+1][r]=v.y; As[kq*4+2][r]=v.z; As[kq*4+3][r]=v.w;
    }
    #pragma unroll
    for (int it=0; it<2; it++){
      int fl = tid + it*256; int r = fl>>3; int kq = fl&7;
      float4 v = *(const float4*)(W + (size_t)(n0+r)*ldw + kc + kq*4);
      Bs[kq*4+0][r]=v.x; Bs[kq*4+1][r]=v.y; Bs[kq*4+2][r]=v.z; Bs[kq*4+3][r]=v.w;
    }
    __syncthreads();
    #pragma unroll
    for (int k=0;k<32;k++){
      float a[8], b[4];
      *(float4*)(a)   = *(const float4*)(&As[k][tm*8]);
      *(float4*)(a+4) = *(const float4*)(&As[k][tm*8+4]);
      *(float4*)(b)   = *(const float4*)(&Bs[k][tn*4]);
      #pragma unroll
      for (int i=0;i<8;i++){
        #pragma unroll
        for (int j=0;j<4;j++) acc[i][j] += a[i]*b[j];
      }
    }
    __syncthreads();
  }
  float4 bv = *(const float4*)(bias + n0 + tn*4);
  #pragma unroll
  for (int i=0;i<8;i++){
    float4 o = make_float4(acc[i][0]+bv.x, acc[i][1]+bv.y, acc[i][2]+bv.z, acc[i][3]+bv.w);
    *(float4*)(C + (size_t)(m0+tm*8+i)*ldc + n0 + tn*4) = o;
  }
}

// highway elementwise: sub = g*relu(zt) + (1-g)*sub
__global__ __launch_bounds__(256)
void k_hwelt(const float* __restrict__ hwz, float* __restrict__ sub){
  const int idx = blockIdx.x*256 + threadIdx.x;
  const int m = idx >> 7, j4 = idx & 127;
  float4 s  = ((const float4*)sub)[idx];
  float4 zt = ((const float4*)hwz)[(size_t)m*256 + j4];
  float4 zg = ((const float4*)hwz)[(size_t)m*256 + 128 + j4];
  float4 o;
  { float g=sigf(zg.x), tr=fmaxf(zt.x,0.f); o.x = g*tr + (1.f-g)*s.x; }
  { float g=sigf(zg.y), tr=fmaxf(zt.y,0.f); o.y = g*tr + (1.f-g)*s.y; }
  { float g=sigf(zg.z), tr=fmaxf(zt.z,0.f); o.z = g*tr + (1.f-g)*s.z; }
  { float g=sigf(zg.w), tr=fmaxf(zt.w,0.f); o.w = g*tr + (1.f-g)*s.w; }
  ((float4*)sub)[idx] = o;
}

// assemble padded word input
__global__ void k_wasm(const int* __restrict__ wmap, const float* __restrict__ weW,
                       const float* __restrict__ sub, float* __restrict__ w){
  const int m = blockIdx.x;
  const int wi = wmap[m];
  for (int col=threadIdx.x; col<DWPn; col+=256){
    float v = 0.f;
    if (col < 100)      v = weW[(size_t)wi*100 + col];
    else if (col < 612) v = sub[(size_t)m*512 + (col-100)];
    w[(size_t)m*DWPn + col] = v;
  }
}

// crf[m][a][b] = em[m][b] + trans[a][b] ; em ld=64
__global__ __launch_bounds__(256)
void k_crf(const float* __restrict__ em, const float* __restrict__ trans,
           float* __restrict__ out){
  const int m = blockIdx.x;
  __shared__ float er[TAGSn];
  if (threadIdx.x < TAGSn) er[threadIdx.x] = em[(size_t)m*64 + threadIdx.x];
  __syncthreads();
  float* o = out + (size_t)m*2500;
  for (int r=threadIdx.x; r<2500; r+=256)
    o[r] = er[r % TAGSn] + trans[r];
}

// int tail outputs as floats
__global__ void k_tail(const int* __restrict__ tm, const int* __restrict__ ln,
                       const int* __restrict__ tc, float* __restrict__ out){
  const int i = blockIdx.x*256 + threadIdx.x;
  if (i < 8192)       out[i] = (float)tm[i];
  else if (i < 8256)  out[i] = (float)ln[i-8192];
  else if (i < 16448) out[i] = (float)tc[i-8256];
}

// ---------------------------------------------------------------------------
extern "C" void kernel_launch(void* const* d_in, const int* in_sizes, int n_in,
                              void* d_out, int out_size, void* d_ws, size_t ws_size,
                              hipStream_t stream){
  (void)in_sizes; (void)n_in; (void)out_size; (void)ws_size;
  const int*   wmap   = (const int*)d_in[0];
  const int*   cmapsf = (const int*)d_in[1];
  const int*   cmapsb = (const int*)d_in[2];
  const float* cmakf  = (const float*)d_in[3];
  const float* cmakb  = (const float*)d_in[4];
  const int*   tmaps  = (const int*)d_in[5];
  const int*   tmapc  = (const int*)d_in[6];
  const int*   lengths= (const int*)d_in[7];
  const float* ceW    = (const float*)d_in[8];
  const float* fcWih  = (const float*)d_in[9];
  const float* fcWhh  = (const float*)d_in[10];
  const float* fcb    = (const float*)d_in[11];
  const float* bcWih  = (const float*)d_in[12];
  const float* bcWhh  = (const float*)d_in[13];
  const float* bcb    = (const float*)d_in[14];
  const float* weW    = (const float*)d_in[15];
  const float* wfWih  = (const float*)d_in[16];
  const float* wfWhh  = (const float*)d_in[17];
  const float* wfb    = (const float*)d_in[18];
  const float* wbWih  = (const float*)d_in[19];
  const float* wbWhh  = (const float*)d_in[20];
  const float* wbb    = (const float*)d_in[21];
  const float* hwWt   = (const float*)d_in[22];
  const float* hwbt   = (const float*)d_in[23];
  const float* hwWg   = (const float*)d_in[24];
  const float* hwbg   = (const float*)d_in[25];
  const float* emW    = (const float*)d_in[26];
  const float* emb    = (const float*)d_in[27];
  const float* trans  = (const float*)d_in[28];

  // workspace layout (floats)
  float* p = (float*)d_ws;
  size_t o = 0;
  float* CWf  = p + o; o += 100*1024;
  float* CWb  = p + o; o += 100*1024;
  unsigned short* W8cf = (unsigned short*)(p + o); o += 65536;   // 1024*256 bytes
  unsigned short* W8cb = (unsigned short*)(p + o); o += 65536;
  unsigned short* W8wf = (unsigned short*)(p + o); o += 65536;
  unsigned short* W8wb = (unsigned short*)(p + o); o += 65536;
  float* Wpf  = p + o; o += 1024*DWPn;
  float* Wpb  = p + o; o += 1024*DWPn;
  int*   posf = (int*)(p + o); o += 64*512;
  int*   posb = (int*)(p + o); o += 64*512;
  float* sub  = p + o; o += (size_t)64*128*512;   // reused later as hout
  float* hwz  = p + o; o += (size_t)8192*1024;    // reused later as wXf
  float* wq   = p + o; o += (size_t)8192*DWPn;    // reused later as em/emWp/embp
  float* wXb  = p + o; o += (size_t)8192*1024;
  float* wXf  = hwz;            // alias: hwz dead after k_hwelt
  float* hout = sub;            // alias: sub dead after k_wasm
  float* em   = wq;             // alias: wq dead after word-Xih gemm
  float* emWp = wq + 8192*64;
  float* embp = emWp + 64*512;

  float* out  = (float*)d_out;

  hipMemsetAsync(sub, 0, (size_t)64*128*512*sizeof(float), stream);

  k_prep_cw <<<dim3(100,2), 256, 0, stream>>>(ceW, fcWih, fcb, bcWih, bcb, CWf, CWb);
  k_prep_w8 <<<dim3(512,4), 256, 0, stream>>>(fcWhh, bcWhh, wfWhh, wbWhh,
                                              W8cf, W8cb, W8wf, W8wb);
  k_pad     <<<dim3(1024,2), 256, 0, stream>>>(wfWih, wbWih, Wpf, Wpb);
  k_prep_pos<<<dim3(64,2), 64, 0, stream>>>(cmakf, cmakb, posf, posb);

  k_char_lstm<<<8, 1024, 0, stream>>>(cmapsf, cmapsb, CWf, CWb,
                                      (const unsigned char*)W8cf, (const unsigned char*)W8cb,
                                      posf, posb, sub);

  // highway
  k_gemm<<<dim3(64,8,2), 256, 0, stream>>>(sub, 512, 512, 512,
                                           hwWt, hwWg, hwbt, hwbg,
                                           hwz, hwz+512, 1024);
  k_hwelt<<<4096, 256, 0, stream>>>(hwz, sub);

  k_wasm<<<8192, 256, 0, stream>>>(wmap, weW, sub, wq);

  // word input projections
  k_gemm<<<dim3(64,16,2), 256, 0, stream>>>(wq, DWPn, DWPn, DWPn,
                                            Wpf, Wpb, wfb, wbb,
                                            wXf, wXb, 1024);

  k_word_lstm<<<64, 1024, 0, stream>>>(wXf, wXb,
                                       (const unsigned char*)W8wf, (const unsigned char*)W8wb,
                                       hout);

  // em = hout @ emW^T + emb (padded to 64 tags), ld 64
  k_pad_em<<<64, 256, 0, stream>>>(emW, emb, emWp, embp);
  k_gemm<<<dim3(64,1,1), 256, 0, stream>>>(hout, 512, 512, 512,
                                           emWp, emWp, embp, embp,
                                           em, em, 64);

  k_crf<<<8192, 256, 0, stream>>>(em, trans, out);
  k_tail<<<65, 256, 0, stream>>>(tmaps, lengths, tmapc, out + (size_t)20480000);
}

// Round 8
// 1468.829 us; speedup vs baseline: 1.4366x; 1.4366x over previous
//
#include <hip/hip_runtime.h>
#include <math.h>

#define Bn 64
#define Tn 128
#define TCn 512
#define CEn 64
#define CHn 256
#define TAGSn 50
#define DWPn 640   // word-LSTM input dim padded 612 -> 640

typedef float f32x4 __attribute__((ext_vector_type(4)));

__device__ __forceinline__ float sigf(float x){ return 1.0f/(1.0f+expf(-x)); }

// fast gate nonlinearities: v_exp_f32 + v_rcp_f32, endpoint-safe
__device__ __forceinline__ float fsig(float x){
  return __builtin_amdgcn_rcpf(1.f + exp2f(-1.4426950408889634f*x));
}
__device__ __forceinline__ float ftanh(float x){
  return 1.f - 2.f*__builtin_amdgcn_rcpf(1.f + exp2f(2.885390081777927f*x));
}

// barrier that drains only LDS (keeps global loads/stores in flight)
__device__ __forceinline__ void bar_lds(){
  asm volatile("s_waitcnt lgkmcnt(0)\n\ts_barrier" ::: "memory");
}

// float -> fp8 e4m3 byte via HW converter
__device__ __forceinline__ unsigned char hw_fp8(float x){
  return (unsigned char)(__builtin_amdgcn_cvt_pk_fp8_f32(x, x, 0, false) & 0xff);
}

// float -> OCP e4m3fn (RNE, denormal-correct, saturating) — prep kernels only
__device__ __forceinline__ unsigned f2e4m3(float x){
  unsigned s = (__float_as_uint(x) >> 24) & 0x80u;
  float ax = fabsf(x);
  if (ax < 0.015625f){
    int q = (int)rintf(ax * 512.f);
    if (q >= 8) return s | 0x08u;
    return s | (unsigned)q;
  }
  if (ax > 464.f) return s | 0x7eu;
  int e; float mfr = frexpf(ax, &e);
  int q = (int)rintf(mfr * 16.f);
  int E = e + 6;
  if (q == 16){ q = 8; E += 1; }
  if (E > 15 || (E == 15 && q == 15)) return s | 0x7eu;
  return s | (unsigned)((E<<3) | (q - 8));
}

// ---------------------------------------------------------------------------
// CW[d][c][u*4+k] = b_d[k*256+u] + sum_e ceW[c][e]*Wih_d[k*256+u][e]
__global__ void k_prep_cw(const float* __restrict__ ceW,
                          const float* __restrict__ Wf, const float* __restrict__ bf,
                          const float* __restrict__ Wb, const float* __restrict__ bb,
                          float* __restrict__ CWf, float* __restrict__ CWb){
  const int c = blockIdx.x, u = threadIdx.x;
  const float* Wih  = blockIdx.y ? Wb : Wf;
  const float* bias = blockIdx.y ? bb : bf;
  float*       CW   = blockIdx.y ? CWb : CWf;
  __shared__ float ce[CEn];
  if (u < CEn) ce[u] = ceW[c*CEn + u];
  __syncthreads();
  float a[4];
  #pragma unroll
  for (int k=0;k<4;k++){
    const float* wr = Wih + (size_t)(k*CHn+u)*CEn;
    float s = bias[k*CHn+u];
    #pragma unroll 4
    for (int e=0;e<CEn;e++) s += ce[e]*wr[e];
    a[k]=s;
  }
  ((float4*)CW)[c*CHn+u] = make_float4(a[0],a[1],a[2],a[3]);
}

// fp8 e4m3 Whh (plain row order): out[n][k] byte = e4m3(Whh[n][k])
// grid (512,4) x 256: each thread converts 2 consecutive elements
__global__ void k_prep_w8(const float* __restrict__ W0, const float* __restrict__ W1,
                          const float* __restrict__ W2, const float* __restrict__ W3,
                          unsigned short* __restrict__ O0, unsigned short* __restrict__ O1,
                          unsigned short* __restrict__ O2, unsigned short* __restrict__ O3){
  const int w = blockIdx.y;
  const float* W = (w==0)?W0:(w==1)?W1:(w==2)?W2:W3;
  unsigned short* O = (w==0)?O0:(w==1)?O1:(w==2)?O2:O3;
  const int i = blockIdx.x*256 + threadIdx.x;      // 131072 pairs
  const float a = W[2*i], b = W[2*i+1];
  O[i] = (unsigned short)(f2e4m3(a) | (f2e4m3(b)<<8));
}

// pad word Wih (1024,612) -> (1024,640)
__global__ void k_pad(const float* __restrict__ Wf, const float* __restrict__ Wb,
                      float* __restrict__ Pf, float* __restrict__ Pb){
  const int j = blockIdx.x;
  const float* Win  = blockIdx.y ? Wb : Wf;
  float*       Wout = blockIdx.y ? Pb : Pf;
  for (int col=threadIdx.x; col<DWPn; col+=256)
    Wout[(size_t)j*DWPn+col] = (col<612) ? Win[(size_t)j*612+col] : 0.f;
}

// pad emW (50,512)->(64,512), emb (50)->(64)
__global__ void k_pad_em(const float* __restrict__ emW, const float* __restrict__ emb,
                         float* __restrict__ Wp, float* __restrict__ bp){
  const int j = blockIdx.x;
  for (int col=threadIdx.x; col<512; col+=256)
    Wp[(size_t)j*512+col] = (j<TAGSn) ? emW[(size_t)j*512+col] : 0.f;
  if (threadIdx.x==0) bp[j] = (j<TAGSn) ? emb[j] : 0.f;
}

// stable-compaction ranks from cmakers only; grid (64,2), 64 threads (1 wave)
__global__ void k_prep_pos(const float* __restrict__ cmf, const float* __restrict__ cmb,
                           int* __restrict__ pf, int* __restrict__ pb){
  const float* cm = blockIdx.y ? cmb : cmf;
  int* pos        = blockIdx.y ? pb : pf;
  const int n = blockIdx.x, lane = threadIdx.x;
  int base = 0;
  for (int c=0;c<TCn/64;c++){
    int t = c*64 + lane;
    bool m = cm[n*TCn+t] != 0.f;
    unsigned long long bal = __ballot(m);
    int before = __popcll(bal & ((1ULL<<lane)-1ULL));
    int r = base + before;
    pos[n*TCn+t] = (m && r < Tn) ? r : -1;
    base += __popcll(bal);
  }
}

// ---------------------------------------------------------------------------
// char LSTM via MFMA, fp8 register-resident weights, M=4 rows/block (R6
// structure) + next-step prefetch + LDS-only barriers + HW fp8 convert.
// 32 blocks = dir(2) x rowgroup(16, 4 seqs each). 1024 threads = 16 waves.
__global__ __launch_bounds__(1024, 4)
void k_char_lstm(const int* __restrict__ cmf, const int* __restrict__ cmb,
                 const float* __restrict__ CWf, const float* __restrict__ CWb,
                 const unsigned char* __restrict__ W8f, const unsigned char* __restrict__ W8b,
                 const int* __restrict__ posf, const int* __restrict__ posb,
                 float* __restrict__ sub){
  const int dir = blockIdx.x >> 4, mg = blockIdx.x & 15;
  const int n0 = mg*4;
  const int t1 = threadIdx.x;
  const int wv = t1 >> 6, lane = t1 & 63;
  const int m = lane & 15, g = lane >> 4;
  const int*    cm  = dir ? cmb : cmf;
  const float4* CW  = (const float4*)(dir ? CWb : CWf);
  const unsigned char* W8 = dir ? W8b : W8f;
  const int*    pos = dir ? posb : posf;
  const int dofs = dir ? CHn : 0;

  __shared__ float zbuf[4][1040];
  __shared__ unsigned long hbufl[2][16][32];   // fp8 h, chunk index XOR row

  // register-resident B fragments: B[k][n]=Whh[n][k], n=wv*64+nt*16+m, k=kt*32+g*8+i
  long Bfr[4][8];
  #pragma unroll
  for (int nt=0;nt<4;nt++)
    #pragma unroll
    for (int kt=0;kt<8;kt++)
      Bfr[nt][kt] = *(const long*)(W8 + (size_t)(wv*64 + nt*16 + m)*256 + kt*32 + g*8);

  ((unsigned long*)hbufl)[t1] = 0ul;   // zero both buffers (1024 longs)
  const int u = t1 & 255, rw = t1 >> 8;
  const int seq = n0 + rw;
  float cst = 0.f;
  int par = 0;
  __syncthreads();

  // step-0 inputs
  int    pp = pos[seq*TCn];
  int    ci = cm[seq*TCn];
  float4 cw = CW[(size_t)ci*CHn + u];

  for (int t=0;t<TCn;t++){
    // prefetch step t+1 (full-step latency cover)
    const int tn_ = (t+1<TCn) ? t+1 : t;
    const int ci2 = cm[seq*TCn + tn_];
    const int pp2 = pos[seq*TCn + tn_];
    const float4 cw2 = CW[(size_t)ci2*CHn + u];
    // MFMA phase
    f32x4 acc[4];
    #pragma unroll
    for (int nt=0;nt<4;nt++){ acc[nt][0]=0.f; acc[nt][1]=0.f; acc[nt][2]=0.f; acc[nt][3]=0.f; }
    #pragma unroll
    for (int kt=0;kt<8;kt++){
      const long afr = (long)hbufl[par][m][(kt*4+g)^m];
      #pragma unroll
      for (int nt=0;nt<4;nt++)
        acc[nt] = __builtin_amdgcn_mfma_f32_16x16x32_fp8_fp8(afr, Bfr[nt][kt], acc[nt], 0,0,0);
    }
    if (g==0){   // rows 0..3 live in lanes 0..15 (reg rg = row)
      #pragma unroll
      for (int nt=0;nt<4;nt++){
        const int col = wv*64 + nt*16 + m;
        #pragma unroll
        for (int rg=0;rg<4;rg++)
          zbuf[rg][col] = acc[nt][rg];
      }
    }
    bar_lds();
    // gate phase: one (row,unit) per thread
    {
      const float zi = zbuf[rw][u      ] + cw.x;
      const float zf = zbuf[rw][256+u  ] + cw.y;
      const float zg = zbuf[rw][512+u  ] + cw.z;
      const float zo = zbuf[rw][768+u  ] + cw.w;
      cst = fsig(zf)*cst + fsig(zi)*ftanh(zg);
      const float hn = fsig(zo)*ftanh(cst);
      ((unsigned char*)&hbufl[par^1][rw][0])[(((u>>3)^rw)<<3)|(u&7)] = hw_fp8(hn);
      if (pp>=0) sub[(size_t)(seq*Tn+pp)*512 + dofs + u] = hn;
    }
    bar_lds();
    pp = pp2; cw = cw2;
    par ^= 1;
  }
}

// ---------------------------------------------------------------------------
// word LSTM via MFMA: scans B=64 steps, batch T=128 rows, M=4 rows/block,
// prefetch + LDS-only barriers + HW fp8 convert. 64 blocks, 1024 threads.
__global__ __launch_bounds__(1024, 4)
void k_word_lstm(const float* __restrict__ wXf, const float* __restrict__ wXb,
                 const unsigned char* __restrict__ W8f, const unsigned char* __restrict__ W8b,
                 float* __restrict__ hout){
  const int dir = blockIdx.x >> 5, mg = blockIdx.x & 31;
  const int t0r = mg*4;
  const int t1 = threadIdx.x;
  const int wv = t1 >> 6, lane = t1 & 63;
  const int m = lane & 15, g = lane >> 4;
  const float* wX = dir ? wXb : wXf;
  const unsigned char* W8 = dir ? W8b : W8f;
  const int dofs = dir ? CHn : 0;

  __shared__ float zbuf[4][1040];
  __shared__ unsigned long hbufl[2][16][32];

  long Bfr[4][8];
  #pragma unroll
  for (int nt=0;nt<4;nt++)
    #pragma unroll
    for (int kt=0;kt<8;kt++)
      Bfr[nt][kt] = *(const long*)(W8 + (size_t)(wv*64 + nt*16 + m)*256 + kt*32 + g*8);

  ((unsigned long*)hbufl)[t1] = 0ul;
  const int u = t1 & 255, rw = t1 >> 8;
  float cst = 0.f;
  int par = 0;
  __syncthreads();

  // step-0 inputs
  {
    const int n = dir ? 63 : 0;
    const float* xp = wX + (size_t)(n*Tn + t0r + rw)*1024 + u;
    // fallthrough into loop with zin preloaded
  }
  const int n00 = dir ? 63 : 0;
  const float* xp0 = wX + (size_t)(n00*Tn + t0r + rw)*1024 + u;
  float4 zin = make_float4(xp0[0], xp0[256], xp0[512], xp0[768]);

  for (int s=0;s<64;s++){
    const int n = dir ? (63-s) : s;
    // prefetch step s+1
    const int sn_ = (s+1<64) ? s+1 : s;
    const int n2 = dir ? (63-sn_) : sn_;
    const float* xp2 = wX + (size_t)(n2*Tn + t0r + rw)*1024 + u;
    const float4 zin2 = make_float4(xp2[0], xp2[256], xp2[512], xp2[768]);
    f32x4 acc[4];
    #pragma unroll
    for (int nt=0;nt<4;nt++){ acc[nt][0]=0.f; acc[nt][1]=0.f; acc[nt][2]=0.f; acc[nt][3]=0.f; }
    #pragma unroll
    for (int kt=0;kt<8;kt++){
      const long afr = (long)hbufl[par][m][(kt*4+g)^m];
      #pragma unroll
      for (int nt=0;nt<4;nt++)
        acc[nt] = __builtin_amdgcn_mfma_f32_16x16x32_fp8_fp8(afr, Bfr[nt][kt], acc[nt], 0,0,0);
    }
    if (g==0){
      #pragma unroll
      for (int nt=0;nt<4;nt++){
        const int col = wv*64 + nt*16 + m;
        #pragma unroll
        for (int rg=0;rg<4;rg++)
          zbuf[rg][col] = acc[nt][rg];
      }
    }
    bar_lds();
    {
      const float zi = zbuf[rw][u      ] + zin.x;
      const float zf = zbuf[rw][256+u  ] + zin.y;
      const float zg = zbuf[rw][512+u  ] + zin.z;
      const float zo = zbuf[rw][768+u  ] + zin.w;
      cst = fsig(zf)*cst + fsig(zi)*ftanh(zg);
      const float hn = fsig(zo)*ftanh(cst);
      ((unsigned char*)&hbufl[par^1][rw][0])[(((u>>3)^rw)<<3)|(u&7)] = hw_fp8(hn);
      hout[(size_t)(n*Tn + t0r + rw)*512 + dofs + u] = hn;
    }
    bar_lds();
    zin = zin2;
    par ^= 1;
  }
}

// ---------------------------------------------------------------------------
// generic fp32 GEMM: C[m][n] = bias[n] + sum_k A[m][k]*W[n][k]
__global__ __launch_bounds__(256)
void k_gemm(const float* __restrict__ A, int lda, int K, int ldw,
            const float* __restrict__ W0, const float* __restrict__ W1,
            const float* __restrict__ b0, const float* __restrict__ b1,
            float* __restrict__ C0, float* __restrict__ C1, int ldc){
  const float* W    = blockIdx.z ? W1 : W0;
  const float* bias = blockIdx.z ? b1 : b0;
  float*       C    = blockIdx.z ? C1 : C0;
  const int m0 = blockIdx.x*128, n0 = blockIdx.y*64;
  __shared__ float As[32][132];
  __shared__ float Bs[32][68];
  const int tid = threadIdx.x;
  float acc[8][4];
  #pragma unroll
  for (int i=0;i<8;i++){
    #pragma unroll
    for (int j=0;j<4;j++) acc[i][j]=0.f;
  }
  const int tm = tid & 15, tn = tid >> 4;
  for (int kc=0; kc<K; kc+=32){
    #pragma unroll
    for (int it=0; it<4; it++){
      int fl = tid + it*256; int r = fl>>3; int kq = fl&7;
      float4 v = *(const float4*)(A + (size_t)(m0+r)*lda + kc + kq*4);
      As[kq*4+0][r]=v.x; As[kq*4+1][r]=v.y; As[kq*4+2][r]=v.z; As[kq*4+3][r]=v.w;
    }
    #pragma unroll
    for (int it=0; it<2; it++){
      int fl = tid + it*256; int r = fl>>3; int kq = fl&7;
      float4 v = *(const float4*)(W + (size_t)(n0+r)*ldw + kc + kq*4);
      Bs[kq*4+0][r]=v.x; Bs[kq*4+1][r]=v.y; Bs[kq*4+2][r]=v.z; Bs[kq*4+3][r]=v.w;
    }
    __syncthreads();
    #pragma unroll
    for (int k=0;k<32;k++){
      float a[8], b[4];
      *(float4*)(a)   = *(const float4*)(&As[k][tm*8]);
      *(float4*)(a+4) = *(const float4*)(&As[k][tm*8+4]);
      *(float4*)(b)   = *(const float4*)(&Bs[k][tn*4]);
      #pragma unroll
      for (int i=0;i<8;i++){
        #pragma unroll
        for (int j=0;j<4;j++) acc[i][j] += a[i]*b[j];
      }
    }
    __syncthreads();
  }
  float4 bv = *(const float4*)(bias + n0 + tn*4);
  #pragma unroll
  for (int i=0;i<8;i++){
    float4 o = make_float4(acc[i][0]+bv.x, acc[i][1]+bv.y, acc[i][2]+bv.z, acc[i][3]+bv.w);
    *(float4*)(C + (size_t)(m0+tm*8+i)*ldc + n0 + tn*4) = o;
  }
}

// highway elementwise: sub = g*relu(zt) + (1-g)*sub
__global__ __launch_bounds__(256)
void k_hwelt(const float* __restrict__ hwz, float* __restrict__ sub){
  const int idx = blockIdx.x*256 + threadIdx.x;
  const int m = idx >> 7, j4 = idx & 127;
  float4 s  = ((const float4*)sub)[idx];
  float4 zt = ((const float4*)hwz)[(size_t)m*256 + j4];
  float4 zg = ((const float4*)hwz)[(size_t)m*256 + 128 + j4];
  float4 o;
  { float g=sigf(zg.x), tr=fmaxf(zt.x,0.f); o.x = g*tr + (1.f-g)*s.x; }
  { float g=sigf(zg.y), tr=fmaxf(zt.y,0.f); o.y = g*tr + (1.f-g)*s.y; }
  { float g=sigf(zg.z), tr=fmaxf(zt.z,0.f); o.z = g*tr + (1.f-g)*s.z; }
  { float g=sigf(zg.w), tr=fmaxf(zt.w,0.f); o.w = g*tr + (1.f-g)*s.w; }
  ((float4*)sub)[idx] = o;
}

// assemble padded word input
__global__ void k_wasm(const int* __restrict__ wmap, const float* __restrict__ weW,
                       const float* __restrict__ sub, float* __restrict__ w){
  const int m = blockIdx.x;
  const int wi = wmap[m];
  for (int col=threadIdx.x; col<DWPn; col+=256){
    float v = 0.f;
    if (col < 100)      v = weW[(size_t)wi*100 + col];
    else if (col < 612) v = sub[(size_t)m*512 + (col-100)];
    w[(size_t)m*DWPn + col] = v;
  }
}

// crf[m][a][b] = em[m][b] + trans[a][b] ; em ld=64
__global__ __launch_bounds__(256)
void k_crf(const float* __restrict__ em, const float* __restrict__ trans,
           float* __restrict__ out){
  const int m = blockIdx.x;
  __shared__ float er[TAGSn];
  if (threadIdx.x < TAGSn) er[threadIdx.x] = em[(size_t)m*64 + threadIdx.x];
  __syncthreads();
  float* o = out + (size_t)m*2500;
  for (int r=threadIdx.x; r<2500; r+=256)
    o[r] = er[r % TAGSn] + trans[r];
}

// int tail outputs as floats
__global__ void k_tail(const int* __restrict__ tm, const int* __restrict__ ln,
                       const int* __restrict__ tc, float* __restrict__ out){
  const int i = blockIdx.x*256 + threadIdx.x;
  if (i < 8192)       out[i] = (float)tm[i];
  else if (i < 8256)  out[i] = (float)ln[i-8192];
  else if (i < 16448) out[i] = (float)tc[i-8256];
}

// ---------------------------------------------------------------------------
extern "C" void kernel_launch(void* const* d_in, const int* in_sizes, int n_in,
                              void* d_out, int out_size, void* d_ws, size_t ws_size,
                              hipStream_t stream){
  (void)in_sizes; (void)n_in; (void)out_size; (void)ws_size;
  const int*   wmap   = (const int*)d_in[0];
  const int*   cmapsf = (const int*)d_in[1];
  const int*   cmapsb = (const int*)d_in[2];
  const float* cmakf  = (const float*)d_in[3];
  const float* cmakb  = (const float*)d_in[4];
  const int*   tmaps  = (const int*)d_in[5];
  const int*   tmapc  = (const int*)d_in[6];
  const int*   lengths= (const int*)d_in[7];
  const float* ceW    = (const float*)d_in[8];
  const float* fcWih  = (const float*)d_in[9];
  const float* fcWhh  = (const float*)d_in[10];
  const float* fcb    = (const float*)d_in[11];
  const float* bcWih  = (const float*)d_in[12];
  const float* bcWhh  = (const float*)d_in[13];
  const float* bcb    = (const float*)d_in[14];
  const float* weW    = (const float*)d_in[15];
  const float* wfWih  = (const float*)d_in[16];
  const float* wfWhh  = (const float*)d_in[17];
  const float* wfb    = (const float*)d_in[18];
  const float* wbWih  = (const float*)d_in[19];
  const float* wbWhh  = (const float*)d_in[20];
  const float* wbb    = (const float*)d_in[21];
  const float* hwWt   = (const float*)d_in[22];
  const float* hwbt   = (const float*)d_in[23];
  const float* hwWg   = (const float*)d_in[24];
  const float* hwbg   = (const float*)d_in[25];
  const float* emW    = (const float*)d_in[26];
  const float* emb    = (const float*)d_in[27];
  const float* trans  = (const float*)d_in[28];

  // workspace layout (floats)
  float* p = (float*)d_ws;
  size_t o = 0;
  float* CWf  = p + o; o += 100*1024;
  float* CWb  = p + o; o += 100*1024;
  unsigned short* W8cf = (unsigned short*)(p + o); o += 65536;   // 1024*256 bytes
  unsigned short* W8cb = (unsigned short*)(p + o); o += 65536;
  unsigned short* W8wf = (unsigned short*)(p + o); o += 65536;
  unsigned short* W8wb = (unsigned short*)(p + o); o += 65536;
  float* Wpf  = p + o; o += 1024*DWPn;
  float* Wpb  = p + o; o += 1024*DWPn;
  int*   posf = (int*)(p + o); o += 64*512;
  int*   posb = (int*)(p + o); o += 64*512;
  float* sub  = p + o; o += (size_t)64*128*512;   // reused later as hout
  float* hwz  = p + o; o += (size_t)8192*1024;    // reused later as wXf
  float* wq   = p + o; o += (size_t)8192*DWPn;    // reused later as em/emWp/embp
  float* wXb  = p + o; o += (size_t)8192*1024;
  float* wXf  = hwz;            // alias: hwz dead after k_hwelt
  float* hout = sub;            // alias: sub dead after k_wasm
  float* em   = wq;             // alias: wq dead after word-Xih gemm
  float* emWp = wq + 8192*64;
  float* embp = emWp + 64*512;

  float* out  = (float*)d_out;

  hipMemsetAsync(sub, 0, (size_t)64*128*512*sizeof(float), stream);

  k_prep_cw <<<dim3(100,2), 256, 0, stream>>>(ceW, fcWih, fcb, bcWih, bcb, CWf, CWb);
  k_prep_w8 <<<dim3(512,4), 256, 0, stream>>>(fcWhh, bcWhh, wfWhh, wbWhh,
                                              W8cf, W8cb, W8wf, W8wb);
  k_pad     <<<dim3(1024,2), 256, 0, stream>>>(wfWih, wbWih, Wpf, Wpb);
  k_prep_pos<<<dim3(64,2), 64, 0, stream>>>(cmakf, cmakb, posf, posb);

  k_char_lstm<<<32, 1024, 0, stream>>>(cmapsf, cmapsb, CWf, CWb,
                                       (const unsigned char*)W8cf, (const unsigned char*)W8cb,
                                       posf, posb, sub);

  // highway
  k_gemm<<<dim3(64,8,2), 256, 0, stream>>>(sub, 512, 512, 512,
                                           hwWt, hwWg, hwbt, hwbg,
                                           hwz, hwz+512, 1024);
  k_hwelt<<<4096, 256, 0, stream>>>(hwz, sub);

  k_wasm<<<8192, 256, 0, stream>>>(wmap, weW, sub, wq);

  // word input projections
  k_gemm<<<dim3(64,16,2), 256, 0, stream>>>(wq, DWPn, DWPn, DWPn,
                                            Wpf, Wpb, wfb, wbb,
                                            wXf, wXb, 1024);

  k_word_lstm<<<64, 1024, 0, stream>>>(wXf, wXb,
                                       (const unsigned char*)W8wf, (const unsigned char*)W8wb,
                                       hout);

  // em = hout @ emW^T + emb (padded to 64 tags), ld 64
  k_pad_em<<<64, 256, 0, stream>>>(emW, emb, emWp, embp);
  k_gemm<<<dim3(64,1,1), 256, 0, stream>>>(hout, 512, 512, 512,
                                           emWp, emWp, embp, embp,
                                           em, em, 64);

  k_crf<<<8192, 256, 0, stream>>>(em, trans, out);
  k_tail<<<65, 256, 0, stream>>>(tmaps, lengths, tmapc, out + (size_t)20480000);
}

// Round 9
// 1430.609 us; speedup vs baseline: 1.4750x; 1.0267x over previous
//
#include <hip/hip_runtime.h>
#include <math.h>

#define Bn 64
#define Tn 128
#define TCn 512
#define CEn 64
#define CHn 256
#define TAGSn 50
#define DWPn 640   // word-LSTM input dim padded 612 -> 640

typedef float f32x4 __attribute__((ext_vector_type(4)));
typedef int   i32x4 __attribute__((ext_vector_type(4)));

#define DEQ 3.07578740157480315e-5f   // 1/(256*127)

__device__ __forceinline__ float sigf(float x){ return 1.0f/(1.0f+expf(-x)); }

// fast gate nonlinearities: v_exp_f32 + v_rcp_f32, endpoint-safe
__device__ __forceinline__ float fsig(float x){
  return __builtin_amdgcn_rcpf(1.f + exp2f(-1.4426950408889634f*x));
}
__device__ __forceinline__ float ftanh(float x){
  return 1.f - 2.f*__builtin_amdgcn_rcpf(1.f + exp2f(2.885390081777927f*x));
}

// barrier that drains only LDS (keeps global loads/stores in flight)
__device__ __forceinline__ void bar_lds(){
  asm volatile("s_waitcnt lgkmcnt(0)\n\ts_barrier" ::: "memory");
}

// ---------------------------------------------------------------------------
// CW[d][c][u*4+k] = b_d[k*256+u] + sum_e ceW[c][e]*Wih_d[k*256+u][e]
__global__ void k_prep_cw(const float* __restrict__ ceW,
                          const float* __restrict__ Wf, const float* __restrict__ bf,
                          const float* __restrict__ Wb, const float* __restrict__ bb,
                          float* __restrict__ CWf, float* __restrict__ CWb){
  const int c = blockIdx.x, u = threadIdx.x;
  const float* Wih  = blockIdx.y ? Wb : Wf;
  const float* bias = blockIdx.y ? bb : bf;
  float*       CW   = blockIdx.y ? CWb : CWf;
  __shared__ float ce[CEn];
  if (u < CEn) ce[u] = ceW[c*CEn + u];
  __syncthreads();
  float a[4];
  #pragma unroll
  for (int k=0;k<4;k++){
    const float* wr = Wih + (size_t)(k*CHn+u)*CEn;
    float s = bias[k*CHn+u];
    #pragma unroll 4
    for (int e=0;e<CEn;e++) s += ce[e]*wr[e];
    a[k]=s;
  }
  ((float4*)CW)[c*CHn+u] = make_float4(a[0],a[1],a[2],a[3]);
}

// i8 Whh: out[n][k] = sat(rint(Whh[n][k]*256)) as signed byte
// grid (512,4) x 256: each thread converts 2 consecutive elements
__global__ void k_prep_w8(const float* __restrict__ W0, const float* __restrict__ W1,
                          const float* __restrict__ W2, const float* __restrict__ W3,
                          unsigned short* __restrict__ O0, unsigned short* __restrict__ O1,
                          unsigned short* __restrict__ O2, unsigned short* __restrict__ O3){
  const int w = blockIdx.y;
  const float* W = (w==0)?W0:(w==1)?W1:(w==2)?W2:W3;
  unsigned short* O = (w==0)?O0:(w==1)?O1:(w==2)?O2:O3;
  const int i = blockIdx.x*256 + threadIdx.x;      // 131072 pairs
  const int b0 = (int)rintf(fminf(fmaxf(W[2*i  ]*256.f,-127.f),127.f));
  const int b1 = (int)rintf(fminf(fmaxf(W[2*i+1]*256.f,-127.f),127.f));
  O[i] = (unsigned short)((b0 & 0xff) | ((b1 & 0xff) << 8));
}

// pad word Wih (1024,612) -> (1024,640)
__global__ void k_pad(const float* __restrict__ Wf, const float* __restrict__ Wb,
                      float* __restrict__ Pf, float* __restrict__ Pb){
  const int j = blockIdx.x;
  const float* Win  = blockIdx.y ? Wb : Wf;
  float*       Wout = blockIdx.y ? Pb : Pf;
  for (int col=threadIdx.x; col<DWPn; col+=256)
    Wout[(size_t)j*DWPn+col] = (col<612) ? Win[(size_t)j*612+col] : 0.f;
}

// pad emW (50,512)->(64,512), emb (50)->(64)
__global__ void k_pad_em(const float* __restrict__ emW, const float* __restrict__ emb,
                         float* __restrict__ Wp, float* __restrict__ bp){
  const int j = blockIdx.x;
  for (int col=threadIdx.x; col<512; col+=256)
    Wp[(size_t)j*512+col] = (j<TAGSn) ? emW[(size_t)j*512+col] : 0.f;
  if (threadIdx.x==0) bp[j] = (j<TAGSn) ? emb[j] : 0.f;
}

// stable-compaction ranks from cmakers only; grid (64,2), 64 threads (1 wave)
__global__ void k_prep_pos(const float* __restrict__ cmf, const float* __restrict__ cmb,
                           int* __restrict__ pf, int* __restrict__ pb){
  const float* cm = blockIdx.y ? cmb : cmf;
  int* pos        = blockIdx.y ? pb : pf;
  const int n = blockIdx.x, lane = threadIdx.x;
  int base = 0;
  for (int c=0;c<TCn/64;c++){
    int t = c*64 + lane;
    bool m = cm[n*TCn+t] != 0.f;
    unsigned long long bal = __ballot(m);
    int before = __popcll(bal & ((1ULL<<lane)-1ULL));
    int r = base + before;
    pos[n*TCn+t] = (m && r < Tn) ? r : -1;
    base += __popcll(bal);
  }
}

// ---------------------------------------------------------------------------
// char LSTM via i8 MFMA (16x16x64), register-pinned weights, M=4 rows/block.
// 32 blocks = dir(2) x rowgroup(16, 4 seqs each). 1024 threads = 16 waves.
// Wave wv owns gate-cols [wv*64, wv*64+64). A rows 4..15 stay zero.
// h LDS: [row][256B], 16B chunks XOR-swizzled by row; packed dword writes.
__global__ __launch_bounds__(1024, 4)
void k_char_lstm(const int* __restrict__ cmf, const int* __restrict__ cmb,
                 const float* __restrict__ CWf, const float* __restrict__ CWb,
                 const unsigned char* __restrict__ W8f, const unsigned char* __restrict__ W8b,
                 const int* __restrict__ posf, const int* __restrict__ posb,
                 float* __restrict__ sub){
  const int dir = blockIdx.x >> 4, mg = blockIdx.x & 15;
  const int n0 = mg*4;
  const int t1 = threadIdx.x;
  const int wv = t1 >> 6, lane = t1 & 63;
  const int m = lane & 15, g = lane >> 4;
  const int*    cm  = dir ? cmb : cmf;
  const float4* CW  = (const float4*)(dir ? CWb : CWf);
  const unsigned char* W8 = dir ? W8b : W8f;
  const int*    pos = dir ? posb : posf;
  const int dofs = dir ? CHn : 0;

  __shared__ float zbuf[4][1040];
  __shared__ unsigned hbw[2][16][64];   // i8 h, 16B chunk idx XOR row

  // register-resident B fragments: B[k][n]=W8[n][k], n=wv*64+nt*16+m, k=kt*64+g*16+i
  i32x4 Bfr[4][4];
  #pragma unroll
  for (int nt=0;nt<4;nt++)
    #pragma unroll
    for (int kt=0;kt<4;kt++)
      Bfr[nt][kt] = *(const i32x4*)(W8 + (size_t)(wv*64 + nt*16 + m)*256 + kt*64 + g*16);

  for (int j=t1; j<2*16*64; j+=1024) ((unsigned*)hbw)[j] = 0u;
  const int u = t1 & 255, rw = t1 >> 8;
  const int seq = n0 + rw;
  float cst = 0.f;
  int par = 0;
  __syncthreads();

  // step-0 inputs
  int    pp = pos[seq*TCn];
  int    ci = cm[seq*TCn];
  float4 cw = CW[(size_t)ci*CHn + u];

  for (int t=0;t<TCn;t++){
    // pin weights in registers (defeats rematerialization)
    #pragma unroll
    for (int nt=0;nt<4;nt++)
      #pragma unroll
      for (int kt=0;kt<4;kt++)
        asm volatile("" : "+v"(Bfr[nt][kt]));
    // prefetch step t+1
    const int tn_ = (t+1<TCn) ? t+1 : t;
    const int ci2 = cm[seq*TCn + tn_];
    const int pp2 = pos[seq*TCn + tn_];
    const float4 cw2 = CW[(size_t)ci2*CHn + u];
    // MFMA phase
    i32x4 acc[4];
    #pragma unroll
    for (int nt=0;nt<4;nt++){ acc[nt][0]=0; acc[nt][1]=0; acc[nt][2]=0; acc[nt][3]=0; }
    const char* hrow = (const char*)&hbw[par][0][0] + m*256;
    #pragma unroll
    for (int kt=0;kt<4;kt++){
      const i32x4 afr = *(const i32x4*)(hrow + (((kt*4+g)^m)<<4));
      #pragma unroll
      for (int nt=0;nt<4;nt++)
        acc[nt] = __builtin_amdgcn_mfma_i32_16x16x64_i8(afr, Bfr[nt][kt], acc[nt], 0,0,0);
    }
    if (g==0){   // rows 0..3 live in lanes 0..15 (reg rg = row)
      #pragma unroll
      for (int nt=0;nt<4;nt++){
        const int col = wv*64 + nt*16 + m;
        #pragma unroll
        for (int rg=0;rg<4;rg++)
          zbuf[rg][col] = (float)acc[nt][rg] * DEQ;
      }
    }
    bar_lds();
    // gate phase: one (row,unit) per thread; all 64 lanes of a wave share rw
    {
      const float zi = zbuf[rw][u      ] + cw.x;
      const float zf = zbuf[rw][256+u  ] + cw.y;
      const float zg = zbuf[rw][512+u  ] + cw.z;
      const float zo = zbuf[rw][768+u  ] + cw.w;
      cst = fsig(zf)*cst + fsig(zi)*ftanh(zg);
      const float hn = fsig(zo)*ftanh(cst);
      // pack 4 lanes' i8 into one dword, lane%4==0 writes (conflict-free)
      unsigned v = (unsigned)(((int)rintf(hn*127.f)) & 0xff);
      unsigned tv = (unsigned)__shfl_xor((int)v,1);
      v = (lane&1) ? ((v<<8)|tv) : ((tv<<8)|v);
      tv = (unsigned)__shfl_xor((int)v,2);
      v = (lane&2) ? ((v<<16)|tv) : ((tv<<16)|v);
      if ((lane&3)==0){
        const int u0 = u & ~3;
        const int dwu = (((u0>>4)^rw)<<2) | ((u0>>2)&3);
        hbw[par^1][rw][dwu] = v;
      }
      if (pp>=0) sub[(size_t)(seq*Tn+pp)*512 + dofs + u] = hn;
    }
    bar_lds();
    pp = pp2; cw = cw2;
    par ^= 1;
  }
}

// ---------------------------------------------------------------------------
// word LSTM via i8 MFMA: scans B=64 steps, batch T=128 rows, M=4 rows/block.
// 64 blocks = dir(2) x rowgroup(32). 1024 threads.
__global__ __launch_bounds__(1024, 4)
void k_word_lstm(const float* __restrict__ wXf, const float* __restrict__ wXb,
                 const unsigned char* __restrict__ W8f, const unsigned char* __restrict__ W8b,
                 float* __restrict__ hout){
  const int dir = blockIdx.x >> 5, mg = blockIdx.x & 31;
  const int t0r = mg*4;
  const int t1 = threadIdx.x;
  const int wv = t1 >> 6, lane = t1 & 63;
  const int m = lane & 15, g = lane >> 4;
  const float* wX = dir ? wXb : wXf;
  const unsigned char* W8 = dir ? W8b : W8f;
  const int dofs = dir ? CHn : 0;

  __shared__ float zbuf[4][1040];
  __shared__ unsigned hbw[2][16][64];

  i32x4 Bfr[4][4];
  #pragma unroll
  for (int nt=0;nt<4;nt++)
    #pragma unroll
    for (int kt=0;kt<4;kt++)
      Bfr[nt][kt] = *(const i32x4*)(W8 + (size_t)(wv*64 + nt*16 + m)*256 + kt*64 + g*16);

  for (int j=t1; j<2*16*64; j+=1024) ((unsigned*)hbw)[j] = 0u;
  const int u = t1 & 255, rw = t1 >> 8;
  float cst = 0.f;
  int par = 0;
  __syncthreads();

  const int n00 = dir ? 63 : 0;
  const float* xp0 = wX + (size_t)(n00*Tn + t0r + rw)*1024 + u;
  float4 zin = make_float4(xp0[0], xp0[256], xp0[512], xp0[768]);

  for (int s=0;s<64;s++){
    #pragma unroll
    for (int nt=0;nt<4;nt++)
      #pragma unroll
      for (int kt=0;kt<4;kt++)
        asm volatile("" : "+v"(Bfr[nt][kt]));
    const int n = dir ? (63-s) : s;
    const int sn_ = (s+1<64) ? s+1 : s;
    const int n2 = dir ? (63-sn_) : sn_;
    const float* xp2 = wX + (size_t)(n2*Tn + t0r + rw)*1024 + u;
    const float4 zin2 = make_float4(xp2[0], xp2[256], xp2[512], xp2[768]);
    i32x4 acc[4];
    #pragma unroll
    for (int nt=0;nt<4;nt++){ acc[nt][0]=0; acc[nt][1]=0; acc[nt][2]=0; acc[nt][3]=0; }
    const char* hrow = (const char*)&hbw[par][0][0] + m*256;
    #pragma unroll
    for (int kt=0;kt<4;kt++){
      const i32x4 afr = *(const i32x4*)(hrow + (((kt*4+g)^m)<<4));
      #pragma unroll
      for (int nt=0;nt<4;nt++)
        acc[nt] = __builtin_amdgcn_mfma_i32_16x16x64_i8(afr, Bfr[nt][kt], acc[nt], 0,0,0);
    }
    if (g==0){
      #pragma unroll
      for (int nt=0;nt<4;nt++){
        const int col = wv*64 + nt*16 + m;
        #pragma unroll
        for (int rg=0;rg<4;rg++)
          zbuf[rg][col] = (float)acc[nt][rg] * DEQ;
      }
    }
    bar_lds();
    {
      const float zi = zbuf[rw][u      ] + zin.x;
      const float zf = zbuf[rw][256+u  ] + zin.y;
      const float zg = zbuf[rw][512+u  ] + zin.z;
      const float zo = zbuf[rw][768+u  ] + zin.w;
      cst = fsig(zf)*cst + fsig(zi)*ftanh(zg);
      const float hn = fsig(zo)*ftanh(cst);
      unsigned v = (unsigned)(((int)rintf(hn*127.f)) & 0xff);
      unsigned tv = (unsigned)__shfl_xor((int)v,1);
      v = (lane&1) ? ((v<<8)|tv) : ((tv<<8)|v);
      tv = (unsigned)__shfl_xor((int)v,2);
      v = (lane&2) ? ((v<<16)|tv) : ((tv<<16)|v);
      if ((lane&3)==0){
        const int u0 = u & ~3;
        const int dwu = (((u0>>4)^rw)<<2) | ((u0>>2)&3);
        hbw[par^1][rw][dwu] = v;
      }
      hout[(size_t)(n*Tn + t0r + rw)*512 + dofs + u] = hn;
    }
    bar_lds();
    zin = zin2;
    par ^= 1;
  }
}

// ---------------------------------------------------------------------------
// generic fp32 GEMM: C[m][n] = bias[n] + sum_k A[m][k]*W[n][k]
__global__ __launch_bounds__(256)
void k_gemm(const float* __restrict__ A, int lda, int K, int ldw,
            const float* __restrict__ W0, const float* __restrict__ W1,
            const float* __restrict__ b0, const float* __restrict__ b1,
            float* __restrict__ C0, float* __restrict__ C1, int ldc){
  const float* W    = blockIdx.z ? W1 : W0;
  const float* bias = blockIdx.z ? b1 : b0;
  float*       C    = blockIdx.z ? C1 : C0;
  const int m0 = blockIdx.x*128, n0 = blockIdx.y*64;
  __shared__ float As[32][132];
  __shared__ float Bs[32][68];
  const int tid = threadIdx.x;
  float acc[8][4];
  #pragma unroll
  for (int i=0;i<8;i++){
    #pragma unroll
    for (int j=0;j<4;j++) acc[i][j]=0.f;
  }
  const int tm = tid & 15, tn = tid >> 4;
  for (int kc=0; kc<K; kc+=32){
    #pragma unroll
    for (int it=0; it<4; it++){
      int fl = tid + it*256; int r = fl>>3; int kq = fl&7;
      float4 v = *(const float4*)(A + (size_t)(m0+r)*lda + kc + kq*4);
      As[kq*4+0][r]=v.x; As[kq*4+1][r]=v.y; As[kq*4+2][r]=v.z; As[kq*4+3][r]=v.w;
    }
    #pragma unroll
    for (int it=0; it<2; it++){
      int fl = tid + it*256; int r = fl>>3; int kq = fl&7;
      float4 v = *(const float4*)(W + (size_t)(n0+r)*ldw + kc + kq*4);
      Bs[kq*4+0][r]=v.x; Bs[kq*4+1][r]=v.y; Bs[kq*4+2][r]=v.z; Bs[kq*4+3][r]=v.w;
    }
    __syncthreads();
    #pragma unroll
    for (int k=0;k<32;k++){
      float a[8], b[4];
      *(float4*)(a)   = *(const float4*)(&As[k][tm*8]);
      *(float4*)(a+4) = *(const float4*)(&As[k][tm*8+4]);
      *(float4*)(b)   = *(const float4*)(&Bs[k][tn*4]);
      #pragma unroll
      for (int i=0;i<8;i++){
        #pragma unroll
        for (int j=0;j<4;j++) acc[i][j] += a[i]*b[j];
      }
    }
    __syncthreads();
  }
  float4 bv = *(const float4*)(bias + n0 + tn*4);
  #pragma unroll
  for (int i=0;i<8;i++){
    float4 o = make_float4(acc[i][0]+bv.x, acc[i][1]+bv.y, acc[i][2]+bv.z, acc[i][3]+bv.w);
    *(float4*)(C + (size_t)(m0+tm*8+i)*ldc + n0 + tn*4) = o;
  }
}

// highway elementwise: sub = g*relu(zt) + (1-g)*sub
__global__ __launch_bounds__(256)
void k_hwelt(const float* __restrict__ hwz, float* __restrict__ sub){
  const int idx = blockIdx.x*256 + threadIdx.x;
  const int m = idx >> 7, j4 = idx & 127;
  float4 s  = ((const float4*)sub)[idx];
  float4 zt = ((const float4*)hwz)[(size_t)m*256 + j4];
  float4 zg = ((const float4*)hwz)[(size_t)m*256 + 128 + j4];
  float4 o;
  { float g=sigf(zg.x), tr=fmaxf(zt.x,0.f); o.x = g*tr + (1.f-g)*s.x; }
  { float g=sigf(zg.y), tr=fmaxf(zt.y,0.f); o.y = g*tr + (1.f-g)*s.y; }
  { float g=sigf(zg.z), tr=fmaxf(zt.z,0.f); o.z = g*tr + (1.f-g)*s.z; }
  { float g=sigf(zg.w), tr=fmaxf(zt.w,0.f); o.w = g*tr + (1.f-g)*s.w; }
  ((float4*)sub)[idx] = o;
}

// assemble padded word input
__global__ void k_wasm(const int* __restrict__ wmap, const float* __restrict__ weW,
                       const float* __restrict__ sub, float* __restrict__ w){
  const int m = blockIdx.x;
  const int wi = wmap[m];
  for (int col=threadIdx.x; col<DWPn; col+=256){
    float v = 0.f;
    if (col < 100)      v = weW[(size_t)wi*100 + col];
    else if (col < 612) v = sub[(size_t)m*512 + (col-100)];
    w[(size_t)m*DWPn + col] = v;
  }
}

// crf[m][a][b] = em[m][b] + trans[a][b] ; em ld=64
__global__ __launch_bounds__(256)
void k_crf(const float* __restrict__ em, const float* __restrict__ trans,
           float* __restrict__ out){
  const int m = blockIdx.x;
  __shared__ float er[TAGSn];
  if (threadIdx.x < TAGSn) er[threadIdx.x] = em[(size_t)m*64 + threadIdx.x];
  __syncthreads();
  float* o = out + (size_t)m*2500;
  for (int r=threadIdx.x; r<2500; r+=256)
    o[r] = er[r % TAGSn] + trans[r];
}

// int tail outputs as floats
__global__ void k_tail(const int* __restrict__ tm, const int* __restrict__ ln,
                       const int* __restrict__ tc, float* __restrict__ out){
  const int i = blockIdx.x*256 + threadIdx.x;
  if (i < 8192)       out[i] = (float)tm[i];
  else if (i < 8256)  out[i] = (float)ln[i-8192];
  else if (i < 16448) out[i] = (float)tc[i-8256];
}

// ---------------------------------------------------------------------------
extern "C" void kernel_launch(void* const* d_in, const int* in_sizes, int n_in,
                              void* d_out, int out_size, void* d_ws, size_t ws_size,
                              hipStream_t stream){
  (void)in_sizes; (void)n_in; (void)out_size; (void)ws_size;
  const int*   wmap   = (const int*)d_in[0];
  const int*   cmapsf = (const int*)d_in[1];
  const int*   cmapsb = (const int*)d_in[2];
  const float* cmakf  = (const float*)d_in[3];
  const float* cmakb  = (const float*)d_in[4];
  const int*   tmaps  = (const int*)d_in[5];
  const int*   tmapc  = (const int*)d_in[6];
  const int*   lengths= (const int*)d_in[7];
  const float* ceW    = (const float*)d_in[8];
  const float* fcWih  = (const float*)d_in[9];
  const float* fcWhh  = (const float*)d_in[10];
  const float* fcb    = (const float*)d_in[11];
  const float* bcWih  = (const float*)d_in[12];
  const float* bcWhh  = (const float*)d_in[13];
  const float* bcb    = (const float*)d_in[14];
  const float* weW    = (const float*)d_in[15];
  const float* wfWih  = (const float*)d_in[16];
  const float* wfWhh  = (const float*)d_in[17];
  const float* wfb    = (const float*)d_in[18];
  const float* wbWih  = (const float*)d_in[19];
  const float* wbWhh  = (const float*)d_in[20];
  const float* wbb    = (const float*)d_in[21];
  const float* hwWt   = (const float*)d_in[22];
  const float* hwbt   = (const float*)d_in[23];
  const float* hwWg   = (const float*)d_in[24];
  const float* hwbg   = (const float*)d_in[25];
  const float* emW    = (const float*)d_in[26];
  const float* emb    = (const float*)d_in[27];
  const float* trans  = (const float*)d_in[28];

  // workspace layout (floats)
  float* p = (float*)d_ws;
  size_t o = 0;
  float* CWf  = p + o; o += 100*1024;
  float* CWb  = p + o; o += 100*1024;
  unsigned short* W8cf = (unsigned short*)(p + o); o += 65536;   // 1024*256 bytes
  unsigned short* W8cb = (unsigned short*)(p + o); o += 65536;
  unsigned short* W8wf = (unsigned short*)(p + o); o += 65536;
  unsigned short* W8wb = (unsigned short*)(p + o); o += 65536;
  float* Wpf  = p + o; o += 1024*DWPn;
  float* Wpb  = p + o; o += 1024*DWPn;
  int*   posf = (int*)(p + o); o += 64*512;
  int*   posb = (int*)(p + o); o += 64*512;
  float* sub  = p + o; o += (size_t)64*128*512;   // reused later as hout
  float* hwz  = p + o; o += (size_t)8192*1024;    // reused later as wXf
  float* wq   = p + o; o += (size_t)8192*DWPn;    // reused later as em/emWp/embp
  float* wXb  = p + o; o += (size_t)8192*1024;
  float* wXf  = hwz;            // alias: hwz dead after k_hwelt
  float* hout = sub;            // alias: sub dead after k_wasm
  float* em   = wq;             // alias: wq dead after word-Xih gemm
  float* emWp = wq + 8192*64;
  float* embp = emWp + 64*512;

  float* out  = (float*)d_out;

  hipMemsetAsync(sub, 0, (size_t)64*128*512*sizeof(float), stream);

  k_prep_cw <<<dim3(100,2), 256, 0, stream>>>(ceW, fcWih, fcb, bcWih, bcb, CWf, CWb);
  k_prep_w8 <<<dim3(512,4), 256, 0, stream>>>(fcWhh, bcWhh, wfWhh, wbWhh,
                                              W8cf, W8cb, W8wf, W8wb);
  k_pad     <<<dim3(1024,2), 256, 0, stream>>>(wfWih, wbWih, Wpf, Wpb);
  k_prep_pos<<<dim3(64,2), 64, 0, stream>>>(cmakf, cmakb, posf, posb);

  k_char_lstm<<<32, 1024, 0, stream>>>(cmapsf, cmapsb, CWf, CWb,
                                       (const unsigned char*)W8cf, (const unsigned char*)W8cb,
                                       posf, posb, sub);

  // highway
  k_gemm<<<dim3(64,8,2), 256, 0, stream>>>(sub, 512, 512, 512,
                                           hwWt, hwWg, hwbt, hwbg,
                                           hwz, hwz+512, 1024);
  k_hwelt<<<4096, 256, 0, stream>>>(hwz, sub);

  k_wasm<<<8192, 256, 0, stream>>>(wmap, weW, sub, wq);

  // word input projections
  k_gemm<<<dim3(64,16,2), 256, 0, stream>>>(wq, DWPn, DWPn, DWPn,
                                            Wpf, Wpb, wfb, wbb,
                                            wXf, wXb, 1024);

  k_word_lstm<<<64, 1024, 0, stream>>>(wXf, wXb,
                                       (const unsigned char*)W8wf, (const unsigned char*)W8wb,
                                       hout);

  // em = hout @ emW^T + emb (padded to 64 tags), ld 64
  k_pad_em<<<64, 256, 0, stream>>>(emW, emb, emWp, embp);
  k_gemm<<<dim3(64,1,1), 256, 0, stream>>>(hout, 512, 512, 512,
                                           emWp, emWp, embp, embp,
                                           em, em, 64);

  k_crf<<<8192, 256, 0, stream>>>(em, trans, out);
  k_tail<<<65, 256, 0, stream>>>(tmaps, lengths, tmapc, out + (size_t)20480000);
}

// Round 10
// 1145.754 us; speedup vs baseline: 1.8417x; 1.2486x over previous
//
#include <hip/hip_runtime.h>
#include <math.h>

#define Bn 64
#define Tn 128
#define TCn 512
#define CEn 64
#define CHn 256
#define TAGSn 50
#define DWPn 640   // word-LSTM input dim padded 612 -> 640

typedef float f32x4 __attribute__((ext_vector_type(4)));
typedef int   i32x4 __attribute__((ext_vector_type(4)));

#define DEQ 3.07578740157480315e-5f   // 1/(256*127)

__device__ __forceinline__ float sigf(float x){ return 1.0f/(1.0f+expf(-x)); }

// fast gate nonlinearities: v_exp_f32 + v_rcp_f32, endpoint-safe
__device__ __forceinline__ float fsig(float x){
  return __builtin_amdgcn_rcpf(1.f + exp2f(-1.4426950408889634f*x));
}
__device__ __forceinline__ float ftanh(float x){
  return 1.f - 2.f*__builtin_amdgcn_rcpf(1.f + exp2f(2.885390081777927f*x));
}

// barrier that drains only LDS (keeps global loads/stores in flight)
__device__ __forceinline__ void bar_lds(){
  asm volatile("s_waitcnt lgkmcnt(0)\n\ts_barrier" ::: "memory");
}

// ---------------------------------------------------------------------------
// CW[d][c][u*4+k] = b_d[k*256+u] + sum_e ceW[c][e]*Wih_d[k*256+u][e]
__global__ void k_prep_cw(const float* __restrict__ ceW,
                          const float* __restrict__ Wf, const float* __restrict__ bf,
                          const float* __restrict__ Wb, const float* __restrict__ bb,
                          float* __restrict__ CWf, float* __restrict__ CWb){
  const int c = blockIdx.x, u = threadIdx.x;
  const float* Wih  = blockIdx.y ? Wb : Wf;
  const float* bias = blockIdx.y ? bb : bf;
  float*       CW   = blockIdx.y ? CWb : CWf;
  __shared__ float ce[CEn];
  if (u < CEn) ce[u] = ceW[c*CEn + u];
  __syncthreads();
  float a[4];
  #pragma unroll
  for (int k=0;k<4;k++){
    const float* wr = Wih + (size_t)(k*CHn+u)*CEn;
    float s = bias[k*CHn+u];
    #pragma unroll 4
    for (int e=0;e<CEn;e++) s += ce[e]*wr[e];
    a[k]=s;
  }
  ((float4*)CW)[c*CHn+u] = make_float4(a[0],a[1],a[2],a[3]);
}

// i8 Whh, gate-tile row permutation for ALL matrices:
//   out row rp = wv*64 + nt*16 + m  <-  src row nt*256 + wv*16 + m
//   value = sat(rint(W*256)) as signed byte. grid (512,4) x 256.
__global__ void k_prep_w8(const float* __restrict__ W0, const float* __restrict__ W1,
                          const float* __restrict__ W2, const float* __restrict__ W3,
                          unsigned short* __restrict__ O0, unsigned short* __restrict__ O1,
                          unsigned short* __restrict__ O2, unsigned short* __restrict__ O3){
  const int w = blockIdx.y;
  const float* W = (w==0)?W0:(w==1)?W1:(w==2)?W2:W3;
  unsigned short* O = (w==0)?O0:(w==1)?O1:(w==2)?O2:O3;
  const int i = blockIdx.x*256 + threadIdx.x;      // 131072 pairs
  const int rp = i >> 7;                           // out row
  const int kp = (i & 127) * 2;                    // k pair base
  const int sr = (((rp>>4)&3)*256) + ((rp>>6)*16) + (rp&15);
  const int b0 = (int)rintf(fminf(fmaxf(W[(size_t)sr*CHn + kp  ]*256.f,-127.f),127.f));
  const int b1 = (int)rintf(fminf(fmaxf(W[(size_t)sr*CHn + kp+1]*256.f,-127.f),127.f));
  O[(size_t)rp*128 + (kp>>1)] = (unsigned short)((b0 & 0xff) | ((b1 & 0xff) << 8));
}

// pad word Wih (1024,612) -> (1024,640)
__global__ void k_pad(const float* __restrict__ Wf, const float* __restrict__ Wb,
                      float* __restrict__ Pf, float* __restrict__ Pb){
  const int j = blockIdx.x;
  const float* Win  = blockIdx.y ? Wb : Wf;
  float*       Wout = blockIdx.y ? Pb : Pf;
  for (int col=threadIdx.x; col<DWPn; col+=256)
    Wout[(size_t)j*DWPn+col] = (col<612) ? Win[(size_t)j*612+col] : 0.f;
}

// pad emW (50,512)->(64,512), emb (50)->(64)
__global__ void k_pad_em(const float* __restrict__ emW, const float* __restrict__ emb,
                         float* __restrict__ Wp, float* __restrict__ bp){
  const int j = blockIdx.x;
  for (int col=threadIdx.x; col<512; col+=256)
    Wp[(size_t)j*512+col] = (j<TAGSn) ? emW[(size_t)j*512+col] : 0.f;
  if (threadIdx.x==0) bp[j] = (j<TAGSn) ? emb[j] : 0.f;
}

// stable-compaction ranks from cmakers only; grid (64,2), 64 threads (1 wave)
__global__ void k_prep_pos(const float* __restrict__ cmf, const float* __restrict__ cmb,
                           int* __restrict__ pf, int* __restrict__ pb){
  const float* cm = blockIdx.y ? cmb : cmf;
  int* pos        = blockIdx.y ? pb : pf;
  const int n = blockIdx.x, lane = threadIdx.x;
  int base = 0;
  for (int c=0;c<TCn/64;c++){
    int t = c*64 + lane;
    bool m = cm[n*TCn+t] != 0.f;
    unsigned long long bal = __ballot(m);
    int before = __popcll(bal & ((1ULL<<lane)-1ULL));
    int r = base + before;
    pos[n*TCn+t] = (m && r < Tn) ? r : -1;
    base += __popcll(bal);
  }
}

// ---------------------------------------------------------------------------
// char LSTM via i8 MFMA, gates fully in-register, 1 barrier/step.
// 32 blocks = dir(2) x group(16, 4 seqs). 1024 threads = 16 waves.
// Seq j lives in A-row 4j; W8 is gate-tile permuted, so lane (m,g) of wave wv
// gets all 4 gates of (seq g, unit wv*16+m) in acc[0..3][0].
__global__ __launch_bounds__(1024, 4)
void k_char_lstm(const int* __restrict__ cmf, const int* __restrict__ cmb,
                 const float* __restrict__ CWf, const float* __restrict__ CWb,
                 const unsigned char* __restrict__ W8f, const unsigned char* __restrict__ W8b,
                 const int* __restrict__ posf, const int* __restrict__ posb,
                 float* __restrict__ sub){
  const int dir = blockIdx.x >> 4, mg = blockIdx.x & 15;
  const int n0 = mg*4;
  const int t1 = threadIdx.x;
  const int wv = t1 >> 6, lane = t1 & 63;
  const int m = lane & 15, g = lane >> 4;
  const int*    cm  = dir ? cmb : cmf;
  const float4* CW  = (const float4*)(dir ? CWb : CWf);
  const unsigned char* W8 = dir ? W8b : W8f;
  const int*    pos = dir ? posb : posf;
  const int dofs = dir ? CHn : 0;

  __shared__ unsigned hbw[2][16][64];   // i8 h, 16B chunk idx XOR row; rows 4j = seq j

  // register-resident B fragments (permuted W8)
  i32x4 Bfr[4][4];
  #pragma unroll
  for (int nt=0;nt<4;nt++)
    #pragma unroll
    for (int kt=0;kt<4;kt++)
      Bfr[nt][kt] = *(const i32x4*)(W8 + (size_t)(wv*64 + nt*16 + m)*256 + kt*64 + g*16);

  for (int j=t1; j<2*16*64; j+=1024) ((unsigned*)hbw)[j] = 0u;
  const int uu = wv*16 + m;    // unit this lane owns
  const int seq = n0 + g;      // seq this lane owns
  float cst = 0.f;
  int par = 0;
  __syncthreads();

  // step-0 inputs
  int    pp = pos[seq*TCn];
  int    ci = cm[seq*TCn];
  float4 cw = CW[(size_t)ci*CHn + uu];

  for (int t=0;t<TCn;t++){
    // pin weights in registers
    #pragma unroll
    for (int nt=0;nt<4;nt++)
      #pragma unroll
      for (int kt=0;kt<4;kt++)
        asm volatile("" : "+v"(Bfr[nt][kt]));
    // prefetch step t+1
    const int tn_ = (t+1<TCn) ? t+1 : t;
    const int ci2 = cm[seq*TCn + tn_];
    const int pp2 = pos[seq*TCn + tn_];
    const float4 cw2 = CW[(size_t)ci2*CHn + uu];
    // MFMA phase: A row m; rows 4j hold seq j, rest zero
    i32x4 acc[4];
    #pragma unroll
    for (int nt=0;nt<4;nt++){ acc[nt][0]=0; acc[nt][1]=0; acc[nt][2]=0; acc[nt][3]=0; }
    const char* hrow = (const char*)&hbw[par][0][0] + m*256;
    #pragma unroll
    for (int kt=0;kt<4;kt++){
      const i32x4 afr = *(const i32x4*)(hrow + (((kt*4+g)^m)<<4));
      #pragma unroll
      for (int nt=0;nt<4;nt++)
        acc[nt] = __builtin_amdgcn_mfma_i32_16x16x64_i8(afr, Bfr[nt][kt], acc[nt], 0,0,0);
    }
    // gate phase: all in-register, one (seq,unit) per lane
    {
      const float zi = (float)acc[0][0]*DEQ + cw.x;
      const float zf = (float)acc[1][0]*DEQ + cw.y;
      const float zg = (float)acc[2][0]*DEQ + cw.z;
      const float zo = (float)acc[3][0]*DEQ + cw.w;
      cst = fsig(zf)*cst + fsig(zi)*ftanh(zg);
      const float hn = fsig(zo)*ftanh(cst);
      // pack 4 lanes' i8 into one dword; lane m%4==0 writes row 4g
      unsigned v = (unsigned)(((int)rintf(hn*127.f)) & 0xff);
      unsigned tv = (unsigned)__shfl_xor((int)v,1);
      v = (lane&1) ? ((v<<8)|tv) : ((tv<<8)|v);
      tv = (unsigned)__shfl_xor((int)v,2);
      v = (lane&2) ? ((v<<16)|tv) : ((tv<<16)|v);
      if ((lane&3)==0){
        const int dwi = ((wv ^ (4*g)) << 2) | (m >> 2);   // chunk wv XOR row, dword m0>>2
        hbw[par^1][4*g][dwi] = v;
      }
      if (pp>=0) sub[(size_t)(seq*Tn+pp)*512 + dofs + uu] = hn;
    }
    bar_lds();
    pp = pp2; cw = cw2;
    par ^= 1;
  }
}

// ---------------------------------------------------------------------------
// word LSTM via i8 MFMA, same in-register-gate structure.
// 64 blocks = dir(2) x group(32, 4 word-positions). 1024 threads.
__global__ __launch_bounds__(1024, 4)
void k_word_lstm(const float* __restrict__ wXf, const float* __restrict__ wXb,
                 const unsigned char* __restrict__ W8f, const unsigned char* __restrict__ W8b,
                 float* __restrict__ hout){
  const int dir = blockIdx.x >> 5, mg = blockIdx.x & 31;
  const int t0r = mg*4;
  const int t1 = threadIdx.x;
  const int wv = t1 >> 6, lane = t1 & 63;
  const int m = lane & 15, g = lane >> 4;
  const float* wX = dir ? wXb : wXf;
  const unsigned char* W8 = dir ? W8b : W8f;
  const int dofs = dir ? CHn : 0;

  __shared__ unsigned hbw[2][16][64];

  i32x4 Bfr[4][4];
  #pragma unroll
  for (int nt=0;nt<4;nt++)
    #pragma unroll
    for (int kt=0;kt<4;kt++)
      Bfr[nt][kt] = *(const i32x4*)(W8 + (size_t)(wv*64 + nt*16 + m)*256 + kt*64 + g*16);

  for (int j=t1; j<2*16*64; j+=1024) ((unsigned*)hbw)[j] = 0u;
  const int uu = wv*16 + m;
  const int row = t0r + g;          // word-position this lane owns
  float cst = 0.f;
  int par = 0;
  __syncthreads();

  const int n00 = dir ? 63 : 0;
  const float* xp0 = wX + (size_t)(n00*Tn + row)*1024 + uu;
  float4 zin = make_float4(xp0[0], xp0[256], xp0[512], xp0[768]);

  for (int s=0;s<64;s++){
    #pragma unroll
    for (int nt=0;nt<4;nt++)
      #pragma unroll
      for (int kt=0;kt<4;kt++)
        asm volatile("" : "+v"(Bfr[nt][kt]));
    const int n = dir ? (63-s) : s;
    const int sn_ = (s+1<64) ? s+1 : s;
    const int n2 = dir ? (63-sn_) : sn_;
    const float* xp2 = wX + (size_t)(n2*Tn + row)*1024 + uu;
    const float4 zin2 = make_float4(xp2[0], xp2[256], xp2[512], xp2[768]);
    i32x4 acc[4];
    #pragma unroll
    for (int nt=0;nt<4;nt++){ acc[nt][0]=0; acc[nt][1]=0; acc[nt][2]=0; acc[nt][3]=0; }
    const char* hrow = (const char*)&hbw[par][0][0] + m*256;
    #pragma unroll
    for (int kt=0;kt<4;kt++){
      const i32x4 afr = *(const i32x4*)(hrow + (((kt*4+g)^m)<<4));
      #pragma unroll
      for (int nt=0;nt<4;nt++)
        acc[nt] = __builtin_amdgcn_mfma_i32_16x16x64_i8(afr, Bfr[nt][kt], acc[nt], 0,0,0);
    }
    {
      const float zi = (float)acc[0][0]*DEQ + zin.x;
      const float zf = (float)acc[1][0]*DEQ + zin.y;
      const float zg = (float)acc[2][0]*DEQ + zin.z;
      const float zo = (float)acc[3][0]*DEQ + zin.w;
      cst = fsig(zf)*cst + fsig(zi)*ftanh(zg);
      const float hn = fsig(zo)*ftanh(cst);
      unsigned v = (unsigned)(((int)rintf(hn*127.f)) & 0xff);
      unsigned tv = (unsigned)__shfl_xor((int)v,1);
      v = (lane&1) ? ((v<<8)|tv) : ((tv<<8)|v);
      tv = (unsigned)__shfl_xor((int)v,2);
      v = (lane&2) ? ((v<<16)|tv) : ((tv<<16)|v);
      if ((lane&3)==0){
        const int dwi = ((wv ^ (4*g)) << 2) | (m >> 2);
        hbw[par^1][4*g][dwi] = v;
      }
      hout[(size_t)(n*Tn + row)*512 + dofs + uu] = hn;
    }
    bar_lds();
    zin = zin2;
    par ^= 1;
  }
}

// ---------------------------------------------------------------------------
// generic fp32 GEMM: C[m][n] = bias[n] + sum_k A[m][k]*W[n][k]
__global__ __launch_bounds__(256)
void k_gemm(const float* __restrict__ A, int lda, int K, int ldw,
            const float* __restrict__ W0, const float* __restrict__ W1,
            const float* __restrict__ b0, const float* __restrict__ b1,
            float* __restrict__ C0, float* __restrict__ C1, int ldc){
  const float* W    = blockIdx.z ? W1 : W0;
  const float* bias = blockIdx.z ? b1 : b0;
  float*       C    = blockIdx.z ? C1 : C0;
  const int m0 = blockIdx.x*128, n0 = blockIdx.y*64;
  __shared__ float As[32][132];
  __shared__ float Bs[32][68];
  const int tid = threadIdx.x;
  float acc[8][4];
  #pragma unroll
  for (int i=0;i<8;i++){
    #pragma unroll
    for (int j=0;j<4;j++) acc[i][j]=0.f;
  }
  const int tm = tid & 15, tn = tid >> 4;
  for (int kc=0; kc<K; kc+=32){
    #pragma unroll
    for (int it=0; it<4; it++){
      int fl = tid + it*256; int r = fl>>3; int kq = fl&7;
      float4 v = *(const float4*)(A + (size_t)(m0+r)*lda + kc + kq*4);
      As[kq*4+0][r]=v.x; As[kq*4+1][r]=v.y; As[kq*4+2][r]=v.z; As[kq*4+3][r]=v.w;
    }
    #pragma unroll
    for (int it=0; it<2; it++){
      int fl = tid + it*256; int r = fl>>3; int kq = fl&7;
      float4 v = *(const float4*)(W + (size_t)(n0+r)*ldw + kc + kq*4);
      Bs[kq*4+0][r]=v.x; Bs[kq*4+1][r]=v.y; Bs[kq*4+2][r]=v.z; Bs[kq*4+3][r]=v.w;
    }
    __syncthreads();
    #pragma unroll
    for (int k=0;k<32;k++){
      float a[8], b[4];
      *(float4*)(a)   = *(const float4*)(&As[k][tm*8]);
      *(float4*)(a+4) = *(const float4*)(&As[k][tm*8+4]);
      *(float4*)(b)   = *(const float4*)(&Bs[k][tn*4]);
      #pragma unroll
      for (int i=0;i<8;i++){
        #pragma unroll
        for (int j=0;j<4;j++) acc[i][j] += a[i]*b[j];
      }
    }
    __syncthreads();
  }
  float4 bv = *(const float4*)(bias + n0 + tn*4);
  #pragma unroll
  for (int i=0;i<8;i++){
    float4 o = make_float4(acc[i][0]+bv.x, acc[i][1]+bv.y, acc[i][2]+bv.z, acc[i][3]+bv.w);
    *(float4*)(C + (size_t)(m0+tm*8+i)*ldc + n0 + tn*4) = o;
  }
}

// highway elementwise: sub = g*relu(zt) + (1-g)*sub
__global__ __launch_bounds__(256)
void k_hwelt(const float* __restrict__ hwz, float* __restrict__ sub){
  const int idx = blockIdx.x*256 + threadIdx.x;
  const int m = idx >> 7, j4 = idx & 127;
  float4 s  = ((const float4*)sub)[idx];
  float4 zt = ((const float4*)hwz)[(size_t)m*256 + j4];
  float4 zg = ((const float4*)hwz)[(size_t)m*256 + 128 + j4];
  float4 o;
  { float g=sigf(zg.x), tr=fmaxf(zt.x,0.f); o.x = g*tr + (1.f-g)*s.x; }
  { float g=sigf(zg.y), tr=fmaxf(zt.y,0.f); o.y = g*tr + (1.f-g)*s.y; }
  { float g=sigf(zg.z), tr=fmaxf(zt.z,0.f); o.z = g*tr + (1.f-g)*s.z; }
  { float g=sigf(zg.w), tr=fmaxf(zt.w,0.f); o.w = g*tr + (1.f-g)*s.w; }
  ((float4*)sub)[idx] = o;
}

// assemble padded word input
__global__ void k_wasm(const int* __restrict__ wmap, const float* __restrict__ weW,
                       const float* __restrict__ sub, float* __restrict__ w){
  const int m = blockIdx.x;
  const int wi = wmap[m];
  for (int col=threadIdx.x; col<DWPn; col+=256){
    float v = 0.f;
    if (col < 100)      v = weW[(size_t)wi*100 + col];
    else if (col < 612) v = sub[(size_t)m*512 + (col-100)];
    w[(size_t)m*DWPn + col] = v;
  }
}

// crf[m][a][b] = em[m][b] + trans[a][b] ; em ld=64
__global__ __launch_bounds__(256)
void k_crf(const float* __restrict__ em, const float* __restrict__ trans,
           float* __restrict__ out){
  const int m = blockIdx.x;
  __shared__ float er[TAGSn];
  if (threadIdx.x < TAGSn) er[threadIdx.x] = em[(size_t)m*64 + threadIdx.x];
  __syncthreads();
  float* o = out + (size_t)m*2500;
  for (int r=threadIdx.x; r<2500; r+=256)
    o[r] = er[r % TAGSn] + trans[r];
}

// int tail outputs as floats
__global__ void k_tail(const int* __restrict__ tm, const int* __restrict__ ln,
                       const int* __restrict__ tc, float* __restrict__ out){
  const int i = blockIdx.x*256 + threadIdx.x;
  if (i < 8192)       out[i] = (float)tm[i];
  else if (i < 8256)  out[i] = (float)ln[i-8192];
  else if (i < 16448) out[i] = (float)tc[i-8256];
}

// ---------------------------------------------------------------------------
extern "C" void kernel_launch(void* const* d_in, const int* in_sizes, int n_in,
                              void* d_out, int out_size, void* d_ws, size_t ws_size,
                              hipStream_t stream){
  (void)in_sizes; (void)n_in; (void)out_size; (void)ws_size;
  const int*   wmap   = (const int*)d_in[0];
  const int*   cmapsf = (const int*)d_in[1];
  const int*   cmapsb = (const int*)d_in[2];
  const float* cmakf  = (const float*)d_in[3];
  const float* cmakb  = (const float*)d_in[4];
  const int*   tmaps  = (const int*)d_in[5];
  const int*   tmapc  = (const int*)d_in[6];
  const int*   lengths= (const int*)d_in[7];
  const float* ceW    = (const float*)d_in[8];
  const float* fcWih  = (const float*)d_in[9];
  const float* fcWhh  = (const float*)d_in[10];
  const float* fcb    = (const float*)d_in[11];
  const float* bcWih  = (const float*)d_in[12];
  const float* bcWhh  = (const float*)d_in[13];
  const float* bcb    = (const float*)d_in[14];
  const float* weW    = (const float*)d_in[15];
  const float* wfWih  = (const float*)d_in[16];
  const float* wfWhh  = (const float*)d_in[17];
  const float* wfb    = (const float*)d_in[18];
  const float* wbWih  = (const float*)d_in[19];
  const float* wbWhh  = (const float*)d_in[20];
  const float* wbb    = (const float*)d_in[21];
  const float* hwWt   = (const float*)d_in[22];
  const float* hwbt   = (const float*)d_in[23];
  const float* hwWg   = (const float*)d_in[24];
  const float* hwbg   = (const float*)d_in[25];
  const float* emW    = (const float*)d_in[26];
  const float* emb    = (const float*)d_in[27];
  const float* trans  = (const float*)d_in[28];

  // workspace layout (floats)
  float* p = (float*)d_ws;
  size_t o = 0;
  float* CWf  = p + o; o += 100*1024;
  float* CWb  = p + o; o += 100*1024;
  unsigned short* W8cf = (unsigned short*)(p + o); o += 65536;   // 1024*256 bytes
  unsigned short* W8cb = (unsigned short*)(p + o); o += 65536;
  unsigned short* W8wf = (unsigned short*)(p + o); o += 65536;
  unsigned short* W8wb = (unsigned short*)(p + o); o += 65536;
  float* Wpf  = p + o; o += 1024*DWPn;
  float* Wpb  = p + o; o += 1024*DWPn;
  int*   posf = (int*)(p + o); o += 64*512;
  int*   posb = (int*)(p + o); o += 64*512;
  float* sub  = p + o; o += (size_t)64*128*512;   // reused later as hout
  float* hwz  = p + o; o += (size_t)8192*1024;    // reused later as wXf
  float* wq   = p + o; o += (size_t)8192*DWPn;    // reused later as em/emWp/embp
  float* wXb  = p + o; o += (size_t)8192*1024;
  float* wXf  = hwz;            // alias: hwz dead after k_hwelt
  float* hout = sub;            // alias: sub dead after k_wasm
  float* em   = wq;             // alias: wq dead after word-Xih gemm
  float* emWp = wq + 8192*64;
  float* embp = emWp + 64*512;

  float* out  = (float*)d_out;

  hipMemsetAsync(sub, 0, (size_t)64*128*512*sizeof(float), stream);

  k_prep_cw <<<dim3(100,2), 256, 0, stream>>>(ceW, fcWih, fcb, bcWih, bcb, CWf, CWb);
  k_prep_w8 <<<dim3(512,4), 256, 0, stream>>>(fcWhh, bcWhh, wfWhh, wbWhh,
                                              W8cf, W8cb, W8wf, W8wb);
  k_pad     <<<dim3(1024,2), 256, 0, stream>>>(wfWih, wbWih, Wpf, Wpb);
  k_prep_pos<<<dim3(64,2), 64, 0, stream>>>(cmakf, cmakb, posf, posb);

  k_char_lstm<<<32, 1024, 0, stream>>>(cmapsf, cmapsb, CWf, CWb,
                                       (const unsigned char*)W8cf, (const unsigned char*)W8cb,
                                       posf, posb, sub);

  // highway
  k_gemm<<<dim3(64,8,2), 256, 0, stream>>>(sub, 512, 512, 512,
                                           hwWt, hwWg, hwbt, hwbg,
                                           hwz, hwz+512, 1024);
  k_hwelt<<<4096, 256, 0, stream>>>(hwz, sub);

  k_wasm<<<8192, 256, 0, stream>>>(wmap, weW, sub, wq);

  // word input projections
  k_gemm<<<dim3(64,16,2), 256, 0, stream>>>(wq, DWPn, DWPn, DWPn,
                                            Wpf, Wpb, wfb, wbb,
                                            wXf, wXb, 1024);

  k_word_lstm<<<64, 1024, 0, stream>>>(wXf, wXb,
                                       (const unsigned char*)W8wf, (const unsigned char*)W8wb,
                                       hout);

  // em = hout @ emW^T + emb (padded to 64 tags), ld 64
  k_pad_em<<<64, 256, 0, stream>>>(emW, emb, emWp, embp);
  k_gemm<<<dim3(64,1,1), 256, 0, stream>>>(hout, 512, 512, 512,
                                           emWp, emWp, embp, embp,
                                           em, em, 64);

  k_crf<<<8192, 256, 0, stream>>>(em, trans, out);
  k_tail<<<65, 256, 0, stream>>>(tmaps, lengths, tmapc, out + (size_t)20480000);
}

// Round 11
// 810.631 us; speedup vs baseline: 2.6031x; 1.4134x over previous
//
#include <hip/hip_runtime.h>
#include <math.h>

#define Bn 64
#define Tn 128
#define TCn 512
#define CEn 64
#define CHn 256
#define TAGSn 50
#define DWPn 640   // word-LSTM input dim padded 612 -> 640

typedef float f32x4 __attribute__((ext_vector_type(4)));
typedef int   i32x4 __attribute__((ext_vector_type(4)));
typedef short bf16x8 __attribute__((ext_vector_type(8)));

#define DEQ 3.07578740157480315e-5f   // 1/(256*127)

__device__ __forceinline__ float sigf(float x){ return 1.0f/(1.0f+expf(-x)); }

__device__ __forceinline__ float fsig(float x){
  return __builtin_amdgcn_rcpf(1.f + exp2f(-1.4426950408889634f*x));
}
__device__ __forceinline__ float ftanh(float x){
  return 1.f - 2.f*__builtin_amdgcn_rcpf(1.f + exp2f(2.885390081777927f*x));
}

// barrier that drains only LDS (keeps global loads/stores in flight)
__device__ __forceinline__ void bar_lds(){
  asm volatile("s_waitcnt lgkmcnt(0)\n\ts_barrier" ::: "memory");
}

// f32 <-> bf16 (RNE)
__device__ __forceinline__ unsigned short f2bf(float x){
  unsigned u = __float_as_uint(x);
  u += 0x7fffu + ((u>>16)&1u);
  return (unsigned short)(u>>16);
}
__device__ __forceinline__ float bf2f(unsigned short h){
  return __uint_as_float(((unsigned)h)<<16);
}

// ---------------------------------------------------------------------------
// CW[d][c][u*4+k] = b_d[k*256+u] + sum_e ceW[c][e]*Wih_d[k*256+u][e]
__global__ void k_prep_cw(const float* __restrict__ ceW,
                          const float* __restrict__ Wf, const float* __restrict__ bf,
                          const float* __restrict__ Wb, const float* __restrict__ bb,
                          float* __restrict__ CWf, float* __restrict__ CWb){
  const int c = blockIdx.x, u = threadIdx.x;
  const float* Wih  = blockIdx.y ? Wb : Wf;
  const float* bias = blockIdx.y ? bb : bf;
  float*       CW   = blockIdx.y ? CWb : CWf;
  __shared__ float ce[CEn];
  if (u < CEn) ce[u] = ceW[c*CEn + u];
  __syncthreads();
  float a[4];
  #pragma unroll
  for (int k=0;k<4;k++){
    const float* wr = Wih + (size_t)(k*CHn+u)*CEn;
    float s = bias[k*CHn+u];
    #pragma unroll 4
    for (int e=0;e<CEn;e++) s += ce[e]*wr[e];
    a[k]=s;
  }
  ((float4*)CW)[c*CHn+u] = make_float4(a[0],a[1],a[2],a[3]);
}

// i8 Whh, gate-tile row permutation:
//   out row rp = wv*64 + nt*16 + m  <-  src row nt*256 + wv*16 + m
__global__ void k_prep_w8(const float* __restrict__ W0, const float* __restrict__ W1,
                          const float* __restrict__ W2, const float* __restrict__ W3,
                          unsigned short* __restrict__ O0, unsigned short* __restrict__ O1,
                          unsigned short* __restrict__ O2, unsigned short* __restrict__ O3){
  const int w = blockIdx.y;
  const float* W = (w==0)?W0:(w==1)?W1:(w==2)?W2:W3;
  unsigned short* O = (w==0)?O0:(w==1)?O1:(w==2)?O2:O3;
  const int i = blockIdx.x*256 + threadIdx.x;      // 131072 pairs
  const int rp = i >> 7;
  const int kp = (i & 127) * 2;
  const int sr = (((rp>>4)&3)*256) + ((rp>>6)*16) + (rp&15);
  const int b0 = (int)rintf(fminf(fmaxf(W[(size_t)sr*CHn + kp  ]*256.f,-127.f),127.f));
  const int b1 = (int)rintf(fminf(fmaxf(W[(size_t)sr*CHn + kp+1]*256.f,-127.f),127.f));
  O[(size_t)rp*128 + (kp>>1)] = (unsigned short)((b0 & 0xff) | ((b1 & 0xff) << 8));
}

// pad word Wih (1024,612) -> bf16 (1024,640)
__global__ void k_pad16(const float* __restrict__ Wf, const float* __restrict__ Wb,
                        unsigned short* __restrict__ Pf, unsigned short* __restrict__ Pb){
  const int j = blockIdx.x;
  const float* Win        = blockIdx.y ? Wb : Wf;
  unsigned short* Wout    = blockIdx.y ? Pb : Pf;
  for (int col=threadIdx.x; col<DWPn; col+=256)
    Wout[(size_t)j*DWPn+col] = (col<612) ? f2bf(Win[(size_t)j*612+col]) : 0;
}

// hwWt/hwWg (512,512) -> bf16
__global__ void k_w16(const float* __restrict__ Wt, const float* __restrict__ Wg,
                      unsigned short* __restrict__ Ot, unsigned short* __restrict__ Og){
  const int j = blockIdx.x;
  const float* W       = blockIdx.y ? Wg : Wt;
  unsigned short* O    = blockIdx.y ? Og : Ot;
  for (int col=threadIdx.x; col<512; col+=256)
    O[(size_t)j*512+col] = f2bf(W[(size_t)j*512+col]);
}

// emW (50,512) -> bf16 (128,512) padded; emb -> fp32 (128) padded
__global__ void k_em16(const float* __restrict__ emW, const float* __restrict__ emb,
                       unsigned short* __restrict__ Wp, float* __restrict__ bp){
  const int j = blockIdx.x;
  for (int col=threadIdx.x; col<512; col+=256)
    Wp[(size_t)j*512+col] = (j<TAGSn) ? f2bf(emW[(size_t)j*512+col]) : 0;
  if (threadIdx.x==0) bp[j] = (j<TAGSn) ? emb[j] : 0.f;
}

// stable-compaction ranks from cmakers only; grid (64,2), 64 threads (1 wave)
__global__ void k_prep_pos(const float* __restrict__ cmf, const float* __restrict__ cmb,
                           int* __restrict__ pf, int* __restrict__ pb){
  const float* cm = blockIdx.y ? cmb : cmf;
  int* pos        = blockIdx.y ? pb : pf;
  const int n = blockIdx.x, lane = threadIdx.x;
  int base = 0;
  for (int c=0;c<TCn/64;c++){
    int t = c*64 + lane;
    bool m = cm[n*TCn+t] != 0.f;
    unsigned long long bal = __ballot(m);
    int before = __popcll(bal & ((1ULL<<lane)-1ULL));
    int r = base + before;
    pos[n*TCn+t] = (m && r < Tn) ? r : -1;
    base += __popcll(bal);
  }
}

// ---------------------------------------------------------------------------
// char LSTM via i8 MFMA, gates fully in-register, 1 barrier/step.
// 32 blocks = dir(2) x group(16, 4 seqs). 1024 threads = 16 waves.
__global__ __launch_bounds__(1024, 4)
void k_char_lstm(const int* __restrict__ cmf, const int* __restrict__ cmb,
                 const float* __restrict__ CWf, const float* __restrict__ CWb,
                 const unsigned char* __restrict__ W8f, const unsigned char* __restrict__ W8b,
                 const int* __restrict__ posf, const int* __restrict__ posb,
                 unsigned short* __restrict__ sub16){
  const int dir = blockIdx.x >> 4, mg = blockIdx.x & 15;
  const int n0 = mg*4;
  const int t1 = threadIdx.x;
  const int wv = t1 >> 6, lane = t1 & 63;
  const int m = lane & 15, g = lane >> 4;
  const int*    cm  = dir ? cmb : cmf;
  const float4* CW  = (const float4*)(dir ? CWb : CWf);
  const unsigned char* W8 = dir ? W8b : W8f;
  const int*    pos = dir ? posb : posf;
  const int dofs = dir ? CHn : 0;

  __shared__ unsigned hbw[2][16][64];   // i8 h, 16B chunk idx XOR row; rows 4j = seq j

  i32x4 Bfr[4][4];
  #pragma unroll
  for (int nt=0;nt<4;nt++)
    #pragma unroll
    for (int kt=0;kt<4;kt++)
      Bfr[nt][kt] = *(const i32x4*)(W8 + (size_t)(wv*64 + nt*16 + m)*256 + kt*64 + g*16);

  for (int j=t1; j<2*16*64; j+=1024) ((unsigned*)hbw)[j] = 0u;
  const int uu = wv*16 + m;
  const int seq = n0 + g;
  float cst = 0.f;
  int par = 0;
  __syncthreads();

  int    pp = pos[seq*TCn];
  int    ci = cm[seq*TCn];
  float4 cw = CW[(size_t)ci*CHn + uu];

  for (int t=0;t<TCn;t++){
    #pragma unroll
    for (int nt=0;nt<4;nt++)
      #pragma unroll
      for (int kt=0;kt<4;kt++)
        asm volatile("" : "+v"(Bfr[nt][kt]));
    const int tn_ = (t+1<TCn) ? t+1 : t;
    const int ci2 = cm[seq*TCn + tn_];
    const int pp2 = pos[seq*TCn + tn_];
    const float4 cw2 = CW[(size_t)ci2*CHn + uu];
    i32x4 acc[4];
    #pragma unroll
    for (int nt=0;nt<4;nt++){ acc[nt][0]=0; acc[nt][1]=0; acc[nt][2]=0; acc[nt][3]=0; }
    const char* hrow = (const char*)&hbw[par][0][0] + m*256;
    #pragma unroll
    for (int kt=0;kt<4;kt++){
      const i32x4 afr = *(const i32x4*)(hrow + (((kt*4+g)^m)<<4));
      #pragma unroll
      for (int nt=0;nt<4;nt++)
        acc[nt] = __builtin_amdgcn_mfma_i32_16x16x64_i8(afr, Bfr[nt][kt], acc[nt], 0,0,0);
    }
    {
      const float zi = (float)acc[0][0]*DEQ + cw.x;
      const float zf = (float)acc[1][0]*DEQ + cw.y;
      const float zg = (float)acc[2][0]*DEQ + cw.z;
      const float zo = (float)acc[3][0]*DEQ + cw.w;
      cst = fsig(zf)*cst + fsig(zi)*ftanh(zg);
      const float hn = fsig(zo)*ftanh(cst);
      unsigned v = (unsigned)(((int)rintf(hn*127.f)) & 0xff);
      unsigned tv = (unsigned)__shfl_xor((int)v,1);
      v = (lane&1) ? ((v<<8)|tv) : ((tv<<8)|v);
      tv = (unsigned)__shfl_xor((int)v,2);
      v = (lane&2) ? ((v<<16)|tv) : ((tv<<16)|v);
      if ((lane&3)==0){
        const int dwi = ((wv ^ (4*g)) << 2) | (m >> 2);
        hbw[par^1][4*g][dwi] = v;
      }
      if (pp>=0) sub16[(size_t)(seq*Tn+pp)*512 + dofs + uu] = f2bf(hn);
    }
    bar_lds();
    pp = pp2; cw = cw2;
    par ^= 1;
  }
}

// ---------------------------------------------------------------------------
// word LSTM via i8 MFMA, in-register gates; writes bf16 hout.
// 64 blocks = dir(2) x group(32, 4 word-positions). 1024 threads.
__global__ __launch_bounds__(1024, 4)
void k_word_lstm(const float* __restrict__ wXf, const float* __restrict__ wXb,
                 const unsigned char* __restrict__ W8f, const unsigned char* __restrict__ W8b,
                 unsigned short* __restrict__ hout16){
  const int dir = blockIdx.x >> 5, mg = blockIdx.x & 31;
  const int t0r = mg*4;
  const int t1 = threadIdx.x;
  const int wv = t1 >> 6, lane = t1 & 63;
  const int m = lane & 15, g = lane >> 4;
  const float* wX = dir ? wXb : wXf;
  const unsigned char* W8 = dir ? W8b : W8f;
  const int dofs = dir ? CHn : 0;

  __shared__ unsigned hbw[2][16][64];

  i32x4 Bfr[4][4];
  #pragma unroll
  for (int nt=0;nt<4;nt++)
    #pragma unroll
    for (int kt=0;kt<4;kt++)
      Bfr[nt][kt] = *(const i32x4*)(W8 + (size_t)(wv*64 + nt*16 + m)*256 + kt*64 + g*16);

  for (int j=t1; j<2*16*64; j+=1024) ((unsigned*)hbw)[j] = 0u;
  const int uu = wv*16 + m;
  const int row = t0r + g;
  float cst = 0.f;
  int par = 0;
  __syncthreads();

  const int n00 = dir ? 63 : 0;
  const float* xp0 = wX + (size_t)(n00*Tn + row)*1024 + uu;
  float4 zin = make_float4(xp0[0], xp0[256], xp0[512], xp0[768]);

  for (int s=0;s<64;s++){
    #pragma unroll
    for (int nt=0;nt<4;nt++)
      #pragma unroll
      for (int kt=0;kt<4;kt++)
        asm volatile("" : "+v"(Bfr[nt][kt]));
    const int n = dir ? (63-s) : s;
    const int sn_ = (s+1<64) ? s+1 : s;
    const int n2 = dir ? (63-sn_) : sn_;
    const float* xp2 = wX + (size_t)(n2*Tn + row)*1024 + uu;
    const float4 zin2 = make_float4(xp2[0], xp2[256], xp2[512], xp2[768]);
    i32x4 acc[4];
    #pragma unroll
    for (int nt=0;nt<4;nt++){ acc[nt][0]=0; acc[nt][1]=0; acc[nt][2]=0; acc[nt][3]=0; }
    const char* hrow = (const char*)&hbw[par][0][0] + m*256;
    #pragma unroll
    for (int kt=0;kt<4;kt++){
      const i32x4 afr = *(const i32x4*)(hrow + (((kt*4+g)^m)<<4));
      #pragma unroll
      for (int nt=0;nt<4;nt++)
        acc[nt] = __builtin_amdgcn_mfma_i32_16x16x64_i8(afr, Bfr[nt][kt], acc[nt], 0,0,0);
    }
    {
      const float zi = (float)acc[0][0]*DEQ + zin.x;
      const float zf = (float)acc[1][0]*DEQ + zin.y;
      const float zg = (float)acc[2][0]*DEQ + zin.z;
      const float zo = (float)acc[3][0]*DEQ + zin.w;
      cst = fsig(zf)*cst + fsig(zi)*ftanh(zg);
      const float hn = fsig(zo)*ftanh(cst);
      unsigned v = (unsigned)(((int)rintf(hn*127.f)) & 0xff);
      unsigned tv = (unsigned)__shfl_xor((int)v,1);
      v = (lane&1) ? ((v<<8)|tv) : ((tv<<8)|v);
      tv = (unsigned)__shfl_xor((int)v,2);
      v = (lane&2) ? ((v<<16)|tv) : ((tv<<16)|v);
      if ((lane&3)==0){
        const int dwi = ((wv ^ (4*g)) << 2) | (m >> 2);
        hbw[par^1][4*g][dwi] = v;
      }
      hout16[(size_t)(n*Tn + row)*512 + dofs + uu] = f2bf(hn);
    }
    bar_lds();
    zin = zin2;
    par ^= 1;
  }
}

// ---------------------------------------------------------------------------
// bf16 MFMA GEMM: C[m][n] = bias[n] + sum_k A[m][k]*W[n][k]
// 128x128 block tile, 256 threads (2x2 waves, 64x64 each), BK=32.
__global__ __launch_bounds__(256)
void k_gemm16(const unsigned short* __restrict__ A, int lda, int K,
              const unsigned short* __restrict__ W0, const unsigned short* __restrict__ W1, int ldw,
              const float* __restrict__ b0, const float* __restrict__ b1,
              float* __restrict__ C0, float* __restrict__ C1, int ldc){
  const unsigned short* W = blockIdx.z ? W1 : W0;
  const float* bias       = blockIdx.z ? b1 : b0;
  float*       C          = blockIdx.z ? C1 : C0;
  const int m0 = blockIdx.x*128, n0 = blockIdx.y*128;
  const int tid = threadIdx.x;
  const int wid = tid >> 6, l = tid & 63;
  const int wr = wid >> 1, wc = wid & 1;
  const int lm = l & 15, lk = l >> 4;
  __shared__ unsigned short As[128][40];   // 80B row stride: 16B-aligned, ~2-way banks
  __shared__ unsigned short Bs[128][40];
  f32x4 acc[4][4];
  #pragma unroll
  for (int i=0;i<4;i++)
    #pragma unroll
    for (int j=0;j<4;j++){ acc[i][j][0]=0.f; acc[i][j][1]=0.f; acc[i][j][2]=0.f; acc[i][j][3]=0.f; }

  const int sr = tid >> 1, sh = (tid & 1) * 16;   // stage: row, 16-elem half
  for (int kc=0; kc<K; kc+=32){
    *(uint4*)&As[sr][sh]   = *(const uint4*)(A + (size_t)(m0+sr)*lda + kc + sh);
    *(uint4*)&As[sr][sh+8] = *(const uint4*)(A + (size_t)(m0+sr)*lda + kc + sh + 8);
    *(uint4*)&Bs[sr][sh]   = *(const uint4*)(W + (size_t)(n0+sr)*ldw + kc + sh);
    *(uint4*)&Bs[sr][sh+8] = *(const uint4*)(W + (size_t)(n0+sr)*ldw + kc + sh + 8);
    __syncthreads();
    bf16x8 af[4], bfr[4];
    #pragma unroll
    for (int mt=0;mt<4;mt++) af[mt]  = *(const bf16x8*)&As[wr*64+mt*16+lm][lk*8];
    #pragma unroll
    for (int nt=0;nt<4;nt++) bfr[nt] = *(const bf16x8*)&Bs[wc*64+nt*16+lm][lk*8];
    #pragma unroll
    for (int mt=0;mt<4;mt++)
      #pragma unroll
      for (int nt=0;nt<4;nt++)
        acc[mt][nt] = __builtin_amdgcn_mfma_f32_16x16x32_bf16(af[mt], bfr[nt], acc[mt][nt], 0,0,0);
    __syncthreads();
  }
  #pragma unroll
  for (int nt=0;nt<4;nt++){
    const int col = n0 + wc*64 + nt*16 + lm;
    const float bv = bias[col];
    #pragma unroll
    for (int mt=0;mt<4;mt++){
      const int r0 = m0 + wr*64 + mt*16 + lk*4;
      #pragma unroll
      for (int rg=0;rg<4;rg++)
        C[(size_t)(r0+rg)*ldc + col] = acc[mt][nt][rg] + bv;
    }
  }
}

// highway elementwise on bf16 sub: sub = g*relu(zt) + (1-g)*sub
__global__ __launch_bounds__(256)
void k_hwelt16(const float* __restrict__ hwz, unsigned short* __restrict__ sub16){
  const int idx = blockIdx.x*256 + threadIdx.x;   // over 8192*512/4
  const int m = idx >> 7, j4 = idx & 127;
  ushort4 s4 = *(const ushort4*)&sub16[(size_t)m*512 + j4*4];
  float4 zt = ((const float4*)hwz)[(size_t)m*256 + j4];
  float4 zg = ((const float4*)hwz)[(size_t)m*256 + 128 + j4];
  ushort4 o;
  { float gg=sigf(zg.x), tr=fmaxf(zt.x,0.f); o.x = f2bf(gg*tr + (1.f-gg)*bf2f(s4.x)); }
  { float gg=sigf(zg.y), tr=fmaxf(zt.y,0.f); o.y = f2bf(gg*tr + (1.f-gg)*bf2f(s4.y)); }
  { float gg=sigf(zg.z), tr=fmaxf(zt.z,0.f); o.z = f2bf(gg*tr + (1.f-gg)*bf2f(s4.z)); }
  { float gg=sigf(zg.w), tr=fmaxf(zt.w,0.f); o.w = f2bf(gg*tr + (1.f-gg)*bf2f(s4.w)); }
  *(ushort4*)&sub16[(size_t)m*512 + j4*4] = o;
}

// assemble padded word input (bf16)
__global__ void k_wasm16(const int* __restrict__ wmap, const float* __restrict__ weW,
                         const unsigned short* __restrict__ sub16,
                         unsigned short* __restrict__ wq16){
  const int m = blockIdx.x;
  const int wi = wmap[m];
  for (int col=threadIdx.x; col<DWPn; col+=256){
    unsigned short v = 0;
    if (col < 100)      v = f2bf(weW[(size_t)wi*100 + col]);
    else if (col < 612) v = sub16[(size_t)m*512 + (col-100)];
    wq16[(size_t)m*DWPn + col] = v;
  }
}

// crf[m][a][b] = em[m][b] + trans[a][b] ; em ld=128
__global__ __launch_bounds__(256)
void k_crf(const float* __restrict__ em, const float* __restrict__ trans,
           float* __restrict__ out){
  const int m = blockIdx.x;
  __shared__ float er[TAGSn];
  if (threadIdx.x < TAGSn) er[threadIdx.x] = em[(size_t)m*128 + threadIdx.x];
  __syncthreads();
  float* o = out + (size_t)m*2500;
  for (int r=threadIdx.x; r<2500; r+=256)
    o[r] = er[r % TAGSn] + trans[r];
}

// int tail outputs as floats
__global__ void k_tail(const int* __restrict__ tm, const int* __restrict__ ln,
                       const int* __restrict__ tc, float* __restrict__ out){
  const int i = blockIdx.x*256 + threadIdx.x;
  if (i < 8192)       out[i] = (float)tm[i];
  else if (i < 8256)  out[i] = (float)ln[i-8192];
  else if (i < 16448) out[i] = (float)tc[i-8256];
}

// ---------------------------------------------------------------------------
extern "C" void kernel_launch(void* const* d_in, const int* in_sizes, int n_in,
                              void* d_out, int out_size, void* d_ws, size_t ws_size,
                              hipStream_t stream){
  (void)in_sizes; (void)n_in; (void)out_size; (void)ws_size;
  const int*   wmap   = (const int*)d_in[0];
  const int*   cmapsf = (const int*)d_in[1];
  const int*   cmapsb = (const int*)d_in[2];
  const float* cmakf  = (const float*)d_in[3];
  const float* cmakb  = (const float*)d_in[4];
  const int*   tmaps  = (const int*)d_in[5];
  const int*   tmapc  = (const int*)d_in[6];
  const int*   lengths= (const int*)d_in[7];
  const float* ceW    = (const float*)d_in[8];
  const float* fcWih  = (const float*)d_in[9];
  const float* fcWhh  = (const float*)d_in[10];
  const float* fcb    = (const float*)d_in[11];
  const float* bcWih  = (const float*)d_in[12];
  const float* bcWhh  = (const float*)d_in[13];
  const float* bcb    = (const float*)d_in[14];
  const float* weW    = (const float*)d_in[15];
  const float* wfWih  = (const float*)d_in[16];
  const float* wfWhh  = (const float*)d_in[17];
  const float* wfb    = (const float*)d_in[18];
  const float* wbWih  = (const float*)d_in[19];
  const float* wbWhh  = (const float*)d_in[20];
  const float* wbb    = (const float*)d_in[21];
  const float* hwWt   = (const float*)d_in[22];
  const float* hwbt   = (const float*)d_in[23];
  const float* hwWg   = (const float*)d_in[24];
  const float* hwbg   = (const float*)d_in[25];
  const float* emW    = (const float*)d_in[26];
  const float* emb    = (const float*)d_in[27];
  const float* trans  = (const float*)d_in[28];

  // workspace layout (float units)
  float* p = (float*)d_ws;
  size_t o = 0;
  float* CWf  = p + o; o += 100*1024;
  float* CWb  = p + o; o += 100*1024;
  unsigned short* W8cf = (unsigned short*)(p + o); o += 65536;   // 1024*256 B
  unsigned short* W8cb = (unsigned short*)(p + o); o += 65536;
  unsigned short* W8wf = (unsigned short*)(p + o); o += 65536;
  unsigned short* W8wb = (unsigned short*)(p + o); o += 65536;
  unsigned short* Wp16f = (unsigned short*)(p + o); o += 1024*DWPn/2;  // bf16 1024x640
  unsigned short* Wp16b = (unsigned short*)(p + o); o += 1024*DWPn/2;
  unsigned short* hw16t = (unsigned short*)(p + o); o += 512*512/2;
  unsigned short* hw16g = (unsigned short*)(p + o); o += 512*512/2;
  unsigned short* em16W = (unsigned short*)(p + o); o += 128*512/2;
  float* embp = p + o; o += 128;
  int*   posf = (int*)(p + o); o += 64*512;
  int*   posb = (int*)(p + o); o += 64*512;
  unsigned short* sub16 = (unsigned short*)(p + o); o += (size_t)8192*512/2;  // also hout16
  float* hwz  = p + o; o += (size_t)8192*1024;                  // also wXf
  unsigned short* wq16 = (unsigned short*)(p + o); o += (size_t)8192*DWPn/2; // also em
  float* wXb  = p + o; o += (size_t)8192*1024;
  float* wXf  = hwz;
  unsigned short* hout16 = sub16;
  float* em   = (float*)wq16;

  float* out  = (float*)d_out;

  hipMemsetAsync(sub16, 0, (size_t)8192*512*2, stream);

  k_prep_cw <<<dim3(100,2), 256, 0, stream>>>(ceW, fcWih, fcb, bcWih, bcb, CWf, CWb);
  k_prep_w8 <<<dim3(512,4), 256, 0, stream>>>(fcWhh, bcWhh, wfWhh, wbWhh,
                                              W8cf, W8cb, W8wf, W8wb);
  k_pad16   <<<dim3(1024,2), 256, 0, stream>>>(wfWih, wbWih, Wp16f, Wp16b);
  k_w16     <<<dim3(512,2), 256, 0, stream>>>(hwWt, hwWg, hw16t, hw16g);
  k_em16    <<<128, 256, 0, stream>>>(emW, emb, em16W, embp);
  k_prep_pos<<<dim3(64,2), 64, 0, stream>>>(cmakf, cmakb, posf, posb);

  k_char_lstm<<<32, 1024, 0, stream>>>(cmapsf, cmapsb, CWf, CWb,
                                       (const unsigned char*)W8cf, (const unsigned char*)W8cb,
                                       posf, posb, sub16);

  // highway: hwz[:,0:512] = sub@Wt^T+bt ; hwz[:,512:1024] = sub@Wg^T+bg
  k_gemm16<<<dim3(64,4,2), 256, 0, stream>>>(sub16, 512, 512,
                                             hw16t, hw16g, 512,
                                             hwbt, hwbg,
                                             hwz, hwz+512, 1024);
  k_hwelt16<<<4096, 256, 0, stream>>>(hwz, sub16);

  k_wasm16<<<8192, 256, 0, stream>>>(wmap, weW, sub16, wq16);

  // word input projections: wX_d = w @ Wih_d^T + b_d
  k_gemm16<<<dim3(64,8,2), 256, 0, stream>>>(wq16, DWPn, DWPn,
                                             Wp16f, Wp16b, DWPn,
                                             wfb, wbb,
                                             wXf, wXb, 1024);

  k_word_lstm<<<64, 1024, 0, stream>>>(wXf, wXb,
                                       (const unsigned char*)W8wf, (const unsigned char*)W8wb,
                                       hout16);

  // em = hout @ emW^T + emb (padded to 128 tags), ld 128
  k_gemm16<<<dim3(64,1,1), 256, 0, stream>>>(hout16, 512, 512,
                                             em16W, em16W, 512,
                                             embp, embp,
                                             em, em, 128);

  k_crf<<<8192, 256, 0, stream>>>(em, trans, out);
  k_tail<<<65, 256, 0, stream>>>(tmaps, lengths, tmapc, out + (size_t)20480000);
}

// Round 12
// 692.694 us; speedup vs baseline: 3.0463x; 1.1703x over previous
//
#include <hip/hip_runtime.h>
#include <math.h>

#define Bn 64
#define Tn 128
#define TCn 512
#define CEn 64
#define CHn 256
#define TAGSn 50
#define DWPn 640   // word-LSTM input dim padded 612 -> 640

typedef float f32x4 __attribute__((ext_vector_type(4)));
typedef int   i32x4 __attribute__((ext_vector_type(4)));
typedef short bf16x8 __attribute__((ext_vector_type(8)));

#define DEQ 3.07578740157480315e-5f   // 1/(256*127)

__device__ __forceinline__ float sigf(float x){ return 1.0f/(1.0f+expf(-x)); }

__device__ __forceinline__ float fsig(float x){
  return __builtin_amdgcn_rcpf(1.f + exp2f(-1.4426950408889634f*x));
}
__device__ __forceinline__ float ftanh(float x){
  return 1.f - 2.f*__builtin_amdgcn_rcpf(1.f + exp2f(2.885390081777927f*x));
}

// barrier that drains only LDS (keeps global loads/stores in flight)
__device__ __forceinline__ void bar_lds(){
  asm volatile("s_waitcnt lgkmcnt(0)\n\ts_barrier" ::: "memory");
}

// f32 <-> bf16 (RNE)
__device__ __forceinline__ unsigned short f2bf(float x){
  unsigned u = __float_as_uint(x);
  u += 0x7fffu + ((u>>16)&1u);
  return (unsigned short)(u>>16);
}
__device__ __forceinline__ float bf2f(unsigned short h){
  return __uint_as_float(((unsigned)h)<<16);
}

// ---------------------------------------------------------------------------
// CW[d][c][u*4+k] = b_d[k*256+u] + sum_e ceW[c][e]*Wih_d[k*256+u][e]
__global__ void k_prep_cw(const float* __restrict__ ceW,
                          const float* __restrict__ Wf, const float* __restrict__ bf,
                          const float* __restrict__ Wb, const float* __restrict__ bb,
                          float* __restrict__ CWf, float* __restrict__ CWb){
  const int c = blockIdx.x, u = threadIdx.x;
  const float* Wih  = blockIdx.y ? Wb : Wf;
  const float* bias = blockIdx.y ? bb : bf;
  float*       CW   = blockIdx.y ? CWb : CWf;
  __shared__ float ce[CEn];
  if (u < CEn) ce[u] = ceW[c*CEn + u];
  __syncthreads();
  float a[4];
  #pragma unroll
  for (int k=0;k<4;k++){
    const float* wr = Wih + (size_t)(k*CHn+u)*CEn;
    float s = bias[k*CHn+u];
    #pragma unroll 4
    for (int e=0;e<CEn;e++) s += ce[e]*wr[e];
    a[k]=s;
  }
  ((float4*)CW)[c*CHn+u] = make_float4(a[0],a[1],a[2],a[3]);
}

// i8 Whh, gate-tile row permutation:
//   out row rp = wv*64 + nt*16 + m  <-  src row nt*256 + wv*16 + m
__global__ void k_prep_w8(const float* __restrict__ W0, const float* __restrict__ W1,
                          const float* __restrict__ W2, const float* __restrict__ W3,
                          unsigned short* __restrict__ O0, unsigned short* __restrict__ O1,
                          unsigned short* __restrict__ O2, unsigned short* __restrict__ O3){
  const int w = blockIdx.y;
  const float* W = (w==0)?W0:(w==1)?W1:(w==2)?W2:W3;
  unsigned short* O = (w==0)?O0:(w==1)?O1:(w==2)?O2:O3;
  const int i = blockIdx.x*256 + threadIdx.x;      // 131072 pairs
  const int rp = i >> 7;
  const int kp = (i & 127) * 2;
  const int sr = (((rp>>4)&3)*256) + ((rp>>6)*16) + (rp&15);
  const int b0 = (int)rintf(fminf(fmaxf(W[(size_t)sr*CHn + kp  ]*256.f,-127.f),127.f));
  const int b1 = (int)rintf(fminf(fmaxf(W[(size_t)sr*CHn + kp+1]*256.f,-127.f),127.f));
  O[(size_t)rp*128 + (kp>>1)] = (unsigned short)((b0 & 0xff) | ((b1 & 0xff) << 8));
}

// pad word Wih (1024,612) -> bf16 (1024,640)
__global__ void k_pad16(const float* __restrict__ Wf, const float* __restrict__ Wb,
                        unsigned short* __restrict__ Pf, unsigned short* __restrict__ Pb){
  const int j = blockIdx.x;
  const float* Win        = blockIdx.y ? Wb : Wf;
  unsigned short* Wout    = blockIdx.y ? Pb : Pf;
  for (int col=threadIdx.x; col<DWPn; col+=256)
    Wout[(size_t)j*DWPn+col] = (col<612) ? f2bf(Win[(size_t)j*612+col]) : 0;
}

// hwWt/hwWg (512,512) -> bf16
__global__ void k_w16(const float* __restrict__ Wt, const float* __restrict__ Wg,
                      unsigned short* __restrict__ Ot, unsigned short* __restrict__ Og){
  const int j = blockIdx.x;
  const float* W       = blockIdx.y ? Wg : Wt;
  unsigned short* O    = blockIdx.y ? Og : Ot;
  for (int col=threadIdx.x; col<512; col+=256)
    O[(size_t)j*512+col] = f2bf(W[(size_t)j*512+col]);
}

// emW (50,512) -> bf16 (128,512) padded; emb -> fp32 (128) padded
__global__ void k_em16(const float* __restrict__ emW, const float* __restrict__ emb,
                       unsigned short* __restrict__ Wp, float* __restrict__ bp){
  const int j = blockIdx.x;
  for (int col=threadIdx.x; col<512; col+=256)
    Wp[(size_t)j*512+col] = (j<TAGSn) ? f2bf(emW[(size_t)j*512+col]) : 0;
  if (threadIdx.x==0) bp[j] = (j<TAGSn) ? emb[j] : 0.f;
}

// stable-compaction ranks from cmakers only; grid (64,2), 64 threads (1 wave)
__global__ void k_prep_pos(const float* __restrict__ cmf, const float* __restrict__ cmb,
                           int* __restrict__ pf, int* __restrict__ pb){
  const float* cm = blockIdx.y ? cmb : cmf;
  int* pos        = blockIdx.y ? pb : pf;
  const int n = blockIdx.x, lane = threadIdx.x;
  int base = 0;
  for (int c=0;c<TCn/64;c++){
    int t = c*64 + lane;
    bool m = cm[n*TCn+t] != 0.f;
    unsigned long long bal = __ballot(m);
    int before = __popcll(bal & ((1ULL<<lane)-1ULL));
    int r = base + before;
    pos[n*TCn+t] = (m && r < Tn) ? r : -1;
    base += __popcll(bal);
  }
}

// ---------------------------------------------------------------------------
// char LSTM via i8 MFMA, gates in-register, 1 barrier/step, unroll-2,
// precomputed LDS addrs, DPP pack. 32 blocks, 1024 threads = 16 waves.
__global__ __launch_bounds__(1024, 4)
void k_char_lstm(const int* __restrict__ cmf, const int* __restrict__ cmb,
                 const float* __restrict__ CWf, const float* __restrict__ CWb,
                 const unsigned char* __restrict__ W8f, const unsigned char* __restrict__ W8b,
                 const int* __restrict__ posf, const int* __restrict__ posb,
                 unsigned short* __restrict__ sub16){
  const int dir = blockIdx.x >> 4, mg = blockIdx.x & 15;
  const int n0 = mg*4;
  const int t1 = threadIdx.x;
  const int wv = t1 >> 6, lane = t1 & 63;
  const int m = lane & 15, g = lane >> 4;
  const int*    cm  = dir ? cmb : cmf;
  const float4* CW  = (const float4*)(dir ? CWb : CWf);
  const unsigned char* W8 = dir ? W8b : W8f;
  const int*    pos = dir ? posb : posf;
  const int dofs = dir ? CHn : 0;

  __shared__ unsigned hbw[2][16][64];   // i8 h, 16B chunk idx XOR row; rows 4j = seq j

  i32x4 Bfr[4][4];
  #pragma unroll
  for (int nt=0;nt<4;nt++)
    #pragma unroll
    for (int kt=0;kt<4;kt++)
      Bfr[nt][kt] = *(const i32x4*)(W8 + (size_t)(wv*64 + nt*16 + m)*256 + kt*64 + g*16);

  for (int j=t1; j<2*16*64; j+=1024) ((unsigned*)hbw)[j] = 0u;
  const int uu = wv*16 + m;
  const int seq = n0 + g;
  const int* cmp  = cm  + seq*TCn;
  const int* posp = pos + seq*TCn;
  unsigned short* subp = sub16 + (size_t)seq*Tn*512 + dofs + uu;

  // precomputed LDS addresses (two parity sets)
  const int dwi = ((wv ^ (4*g)) << 2) | (m >> 2);
  unsigned* wp0 = &hbw[1][4*g][dwi];   // body par=0 writes buf 1
  unsigned* wp1 = &hbw[0][4*g][dwi];
  const i32x4* rp0[4]; const i32x4* rp1[4];
  {
    const char* r0 = (const char*)&hbw[0][0][0] + m*256;
    const char* r1 = (const char*)&hbw[1][0][0] + m*256;
    #pragma unroll
    for (int kt=0;kt<4;kt++){
      const int off = ((kt*4+g)^m)<<4;
      rp0[kt] = (const i32x4*)(r0 + off);
      rp1[kt] = (const i32x4*)(r1 + off);
    }
  }
  float cst = 0.f;
  __syncthreads();

  int    pp = posp[0];
  float4 cw = CW[(size_t)cmp[0]*CHn + uu];

#define CBODY(T, RP, WP) { \
    i32x4 a0 = *(RP)[0], a1 = *(RP)[1], a2 = *(RP)[2], a3 = *(RP)[3]; \
    const int tn_ = ((T)+1 < TCn) ? (T)+1 : (T); \
    const int ci2 = cmp[tn_]; \
    const int pp2 = posp[tn_]; \
    const float4 cw2 = CW[(size_t)ci2*CHn + uu]; \
    i32x4 c0={0,0,0,0}, c1={0,0,0,0}, c2={0,0,0,0}, c3={0,0,0,0}; \
    c0 = __builtin_amdgcn_mfma_i32_16x16x64_i8(a0, Bfr[0][0], c0, 0,0,0); \
    c1 = __builtin_amdgcn_mfma_i32_16x16x64_i8(a0, Bfr[1][0], c1, 0,0,0); \
    c2 = __builtin_amdgcn_mfma_i32_16x16x64_i8(a0, Bfr[2][0], c2, 0,0,0); \
    c3 = __builtin_amdgcn_mfma_i32_16x16x64_i8(a0, Bfr[3][0], c3, 0,0,0); \
    c0 = __builtin_amdgcn_mfma_i32_16x16x64_i8(a1, Bfr[0][1], c0, 0,0,0); \
    c1 = __builtin_amdgcn_mfma_i32_16x16x64_i8(a1, Bfr[1][1], c1, 0,0,0); \
    c2 = __builtin_amdgcn_mfma_i32_16x16x64_i8(a1, Bfr[2][1], c2, 0,0,0); \
    c3 = __builtin_amdgcn_mfma_i32_16x16x64_i8(a1, Bfr[3][1], c3, 0,0,0); \
    c0 = __builtin_amdgcn_mfma_i32_16x16x64_i8(a2, Bfr[0][2], c0, 0,0,0); \
    c1 = __builtin_amdgcn_mfma_i32_16x16x64_i8(a2, Bfr[1][2], c1, 0,0,0); \
    c2 = __builtin_amdgcn_mfma_i32_16x16x64_i8(a2, Bfr[2][2], c2, 0,0,0); \
    c3 = __builtin_amdgcn_mfma_i32_16x16x64_i8(a2, Bfr[3][2], c3, 0,0,0); \
    c0 = __builtin_amdgcn_mfma_i32_16x16x64_i8(a3, Bfr[0][3], c0, 0,0,0); \
    c1 = __builtin_amdgcn_mfma_i32_16x16x64_i8(a3, Bfr[1][3], c1, 0,0,0); \
    c2 = __builtin_amdgcn_mfma_i32_16x16x64_i8(a3, Bfr[2][3], c2, 0,0,0); \
    c3 = __builtin_amdgcn_mfma_i32_16x16x64_i8(a3, Bfr[3][3], c3, 0,0,0); \
    const float zi = fmaf((float)c0[0], DEQ, cw.x); \
    const float zf = fmaf((float)c1[0], DEQ, cw.y); \
    const float zg = fmaf((float)c2[0], DEQ, cw.z); \
    const float zo = fmaf((float)c3[0], DEQ, cw.w); \
    cst = fsig(zf)*cst + fsig(zi)*ftanh(zg); \
    const float hn = fsig(zo)*ftanh(cst); \
    int vv = ((int)rintf(hn*127.f)) & 0xff; \
    int tv = __builtin_amdgcn_mov_dpp(vv, 0xB1, 0xF, 0xF, true); \
    vv = (lane&1) ? ((vv<<8)|tv) : ((tv<<8)|vv); \
    tv = __builtin_amdgcn_mov_dpp(vv, 0x4E, 0xF, 0xF, true); \
    vv = (lane&2) ? ((vv<<16)|tv) : ((tv<<16)|vv); \
    if ((lane&3)==0) *(WP) = (unsigned)vv; \
    if (pp>=0) subp[(size_t)pp*512] = f2bf(hn); \
    bar_lds(); \
    pp = pp2; cw = cw2; }

  for (int t=0;t<TCn;t+=2){
    #pragma unroll
    for (int nt=0;nt<4;nt++)
      #pragma unroll
      for (int kt=0;kt<4;kt++)
        asm volatile("" : "+v"(Bfr[nt][kt]));
    CBODY(t,   rp0, wp0)
    CBODY(t+1, rp1, wp1)
  }
#undef CBODY
}

// ---------------------------------------------------------------------------
// word LSTM via i8 MFMA, same structure; writes bf16 hout. 64 blocks.
__global__ __launch_bounds__(1024, 4)
void k_word_lstm(const float* __restrict__ wXf, const float* __restrict__ wXb,
                 const unsigned char* __restrict__ W8f, const unsigned char* __restrict__ W8b,
                 unsigned short* __restrict__ hout16){
  const int dir = blockIdx.x >> 5, mg = blockIdx.x & 31;
  const int t0r = mg*4;
  const int t1 = threadIdx.x;
  const int wv = t1 >> 6, lane = t1 & 63;
  const int m = lane & 15, g = lane >> 4;
  const float* wX = dir ? wXb : wXf;
  const unsigned char* W8 = dir ? W8b : W8f;
  const int dofs = dir ? CHn : 0;

  __shared__ unsigned hbw[2][16][64];

  i32x4 Bfr[4][4];
  #pragma unroll
  for (int nt=0;nt<4;nt++)
    #pragma unroll
    for (int kt=0;kt<4;kt++)
      Bfr[nt][kt] = *(const i32x4*)(W8 + (size_t)(wv*64 + nt*16 + m)*256 + kt*64 + g*16);

  for (int j=t1; j<2*16*64; j+=1024) ((unsigned*)hbw)[j] = 0u;
  const int uu = wv*16 + m;
  const int row = t0r + g;
  const float* xbase = wX + (size_t)row*1024 + uu;
  unsigned short* hop = hout16 + (size_t)row*512 + dofs + uu;

  const int dwi = ((wv ^ (4*g)) << 2) | (m >> 2);
  unsigned* wp0 = &hbw[1][4*g][dwi];
  unsigned* wp1 = &hbw[0][4*g][dwi];
  const i32x4* rp0[4]; const i32x4* rp1[4];
  {
    const char* r0 = (const char*)&hbw[0][0][0] + m*256;
    const char* r1 = (const char*)&hbw[1][0][0] + m*256;
    #pragma unroll
    for (int kt=0;kt<4;kt++){
      const int off = ((kt*4+g)^m)<<4;
      rp0[kt] = (const i32x4*)(r0 + off);
      rp1[kt] = (const i32x4*)(r1 + off);
    }
  }
  float cst = 0.f;
  __syncthreads();

  {
    const int n00 = dir ? 63 : 0;
    const float* xp0 = xbase + (size_t)n00*131072;
    float4 zin = make_float4(xp0[0], xp0[256], xp0[512], xp0[768]);

#define WBODY(S, RP, WP) { \
    i32x4 a0 = *(RP)[0], a1 = *(RP)[1], a2 = *(RP)[2], a3 = *(RP)[3]; \
    const int n = dir ? (63-(S)) : (S); \
    const int sn_ = ((S)+1 < 64) ? (S)+1 : (S); \
    const int n2 = dir ? (63-sn_) : sn_; \
    const float* xp2 = xbase + (size_t)n2*131072; \
    const float4 zin2 = make_float4(xp2[0], xp2[256], xp2[512], xp2[768]); \
    i32x4 c0={0,0,0,0}, c1={0,0,0,0}, c2={0,0,0,0}, c3={0,0,0,0}; \
    c0 = __builtin_amdgcn_mfma_i32_16x16x64_i8(a0, Bfr[0][0], c0, 0,0,0); \
    c1 = __builtin_amdgcn_mfma_i32_16x16x64_i8(a0, Bfr[1][0], c1, 0,0,0); \
    c2 = __builtin_amdgcn_mfma_i32_16x16x64_i8(a0, Bfr[2][0], c2, 0,0,0); \
    c3 = __builtin_amdgcn_mfma_i32_16x16x64_i8(a0, Bfr[3][0], c3, 0,0,0); \
    c0 = __builtin_amdgcn_mfma_i32_16x16x64_i8(a1, Bfr[0][1], c0, 0,0,0); \
    c1 = __builtin_amdgcn_mfma_i32_16x16x64_i8(a1, Bfr[1][1], c1, 0,0,0); \
    c2 = __builtin_amdgcn_mfma_i32_16x16x64_i8(a1, Bfr[2][1], c2, 0,0,0); \
    c3 = __builtin_amdgcn_mfma_i32_16x16x64_i8(a1, Bfr[3][1], c3, 0,0,0); \
    c0 = __builtin_amdgcn_mfma_i32_16x16x64_i8(a2, Bfr[0][2], c0, 0,0,0); \
    c1 = __builtin_amdgcn_mfma_i32_16x16x64_i8(a2, Bfr[1][2], c1, 0,0,0); \
    c2 = __builtin_amdgcn_mfma_i32_16x16x64_i8(a2, Bfr[2][2], c2, 0,0,0); \
    c3 = __builtin_amdgcn_mfma_i32_16x16x64_i8(a2, Bfr[3][2], c3, 0,0,0); \
    c0 = __builtin_amdgcn_mfma_i32_16x16x64_i8(a3, Bfr[0][3], c0, 0,0,0); \
    c1 = __builtin_amdgcn_mfma_i32_16x16x64_i8(a3, Bfr[1][3], c1, 0,0,0); \
    c2 = __builtin_amdgcn_mfma_i32_16x16x64_i8(a3, Bfr[2][3], c2, 0,0,0); \
    c3 = __builtin_amdgcn_mfma_i32_16x16x64_i8(a3, Bfr[3][3], c3, 0,0,0); \
    const float zi = fmaf((float)c0[0], DEQ, zin.x); \
    const float zf = fmaf((float)c1[0], DEQ, zin.y); \
    const float zg = fmaf((float)c2[0], DEQ, zin.z); \
    const float zo = fmaf((float)c3[0], DEQ, zin.w); \
    cst = fsig(zf)*cst + fsig(zi)*ftanh(zg); \
    const float hn = fsig(zo)*ftanh(cst); \
    int vv = ((int)rintf(hn*127.f)) & 0xff; \
    int tv = __builtin_amdgcn_mov_dpp(vv, 0xB1, 0xF, 0xF, true); \
    vv = (lane&1) ? ((vv<<8)|tv) : ((tv<<8)|vv); \
    tv = __builtin_amdgcn_mov_dpp(vv, 0x4E, 0xF, 0xF, true); \
    vv = (lane&2) ? ((vv<<16)|tv) : ((tv<<16)|vv); \
    if ((lane&3)==0) *(WP) = (unsigned)vv; \
    hop[(size_t)n*65536] = f2bf(hn); \
    bar_lds(); \
    zin = zin2; }

    for (int s=0;s<64;s+=2){
      #pragma unroll
      for (int nt=0;nt<4;nt++)
        #pragma unroll
        for (int kt=0;kt<4;kt++)
          asm volatile("" : "+v"(Bfr[nt][kt]));
      WBODY(s,   rp0, wp0)
      WBODY(s+1, rp1, wp1)
    }
#undef WBODY
  }
}

// ---------------------------------------------------------------------------
// bf16 MFMA GEMM: C[m][n] = bias[n] + sum_k A[m][k]*W[n][k]
// 128x128 block tile, 256 threads (2x2 waves, 64x64 each), BK=32.
__global__ __launch_bounds__(256)
void k_gemm16(const unsigned short* __restrict__ A, int lda, int K,
              const unsigned short* __restrict__ W0, const unsigned short* __restrict__ W1, int ldw,
              const float* __restrict__ b0, const float* __restrict__ b1,
              float* __restrict__ C0, float* __restrict__ C1, int ldc){
  const unsigned short* W = blockIdx.z ? W1 : W0;
  const float* bias       = blockIdx.z ? b1 : b0;
  float*       C          = blockIdx.z ? C1 : C0;
  const int m0 = blockIdx.x*128, n0 = blockIdx.y*128;
  const int tid = threadIdx.x;
  const int wid = tid >> 6, l = tid & 63;
  const int wr = wid >> 1, wc = wid & 1;
  const int lm = l & 15, lk = l >> 4;
  __shared__ unsigned short As[128][40];
  __shared__ unsigned short Bs[128][40];
  f32x4 acc[4][4];
  #pragma unroll
  for (int i=0;i<4;i++)
    #pragma unroll
    for (int j=0;j<4;j++){ acc[i][j][0]=0.f; acc[i][j][1]=0.f; acc[i][j][2]=0.f; acc[i][j][3]=0.f; }

  const int sr = tid >> 1, sh = (tid & 1) * 16;
  for (int kc=0; kc<K; kc+=32){
    *(uint4*)&As[sr][sh]   = *(const uint4*)(A + (size_t)(m0+sr)*lda + kc + sh);
    *(uint4*)&As[sr][sh+8] = *(const uint4*)(A + (size_t)(m0+sr)*lda + kc + sh + 8);
    *(uint4*)&Bs[sr][sh]   = *(const uint4*)(W + (size_t)(n0+sr)*ldw + kc + sh);
    *(uint4*)&Bs[sr][sh+8] = *(const uint4*)(W + (size_t)(n0+sr)*ldw + kc + sh + 8);
    __syncthreads();
    bf16x8 af[4], bfr[4];
    #pragma unroll
    for (int mt=0;mt<4;mt++) af[mt]  = *(const bf16x8*)&As[wr*64+mt*16+lm][lk*8];
    #pragma unroll
    for (int nt=0;nt<4;nt++) bfr[nt] = *(const bf16x8*)&Bs[wc*64+nt*16+lm][lk*8];
    #pragma unroll
    for (int mt=0;mt<4;mt++)
      #pragma unroll
      for (int nt=0;nt<4;nt++)
        acc[mt][nt] = __builtin_amdgcn_mfma_f32_16x16x32_bf16(af[mt], bfr[nt], acc[mt][nt], 0,0,0);
    __syncthreads();
  }
  #pragma unroll
  for (int nt=0;nt<4;nt++){
    const int col = n0 + wc*64 + nt*16 + lm;
    const float bv = bias[col];
    #pragma unroll
    for (int mt=0;mt<4;mt++){
      const int r0 = m0 + wr*64 + mt*16 + lk*4;
      #pragma unroll
      for (int rg=0;rg<4;rg++)
        C[(size_t)(r0+rg)*ldc + col] = acc[mt][nt][rg] + bv;
    }
  }
}

// highway elementwise on bf16 sub: sub = g*relu(zt) + (1-g)*sub
__global__ __launch_bounds__(256)
void k_hwelt16(const float* __restrict__ hwz, unsigned short* __restrict__ sub16){
  const int idx = blockIdx.x*256 + threadIdx.x;
  const int m = idx >> 7, j4 = idx & 127;
  ushort4 s4 = *(const ushort4*)&sub16[(size_t)m*512 + j4*4];
  float4 zt = ((const float4*)hwz)[(size_t)m*256 + j4];
  float4 zg = ((const float4*)hwz)[(size_t)m*256 + 128 + j4];
  ushort4 o;
  { float gg=sigf(zg.x), tr=fmaxf(zt.x,0.f); o.x = f2bf(gg*tr + (1.f-gg)*bf2f(s4.x)); }
  { float gg=sigf(zg.y), tr=fmaxf(zt.y,0.f); o.y = f2bf(gg*tr + (1.f-gg)*bf2f(s4.y)); }
  { float gg=sigf(zg.z), tr=fmaxf(zt.z,0.f); o.z = f2bf(gg*tr + (1.f-gg)*bf2f(s4.z)); }
  { float gg=sigf(zg.w), tr=fmaxf(zt.w,0.f); o.w = f2bf(gg*tr + (1.f-gg)*bf2f(s4.w)); }
  *(ushort4*)&sub16[(size_t)m*512 + j4*4] = o;
}

// assemble padded word input (bf16)
__global__ void k_wasm16(const int* __restrict__ wmap, const float* __restrict__ weW,
                         const unsigned short* __restrict__ sub16,
                         unsigned short* __restrict__ wq16){
  const int m = blockIdx.x;
  const int wi = wmap[m];
  for (int col=threadIdx.x; col<DWPn; col+=256){
    unsigned short v = 0;
    if (col < 100)      v = f2bf(weW[(size_t)wi*100 + col]);
    else if (col < 612) v = sub16[(size_t)m*512 + (col-100)];
    wq16[(size_t)m*DWPn + col] = v;
  }
}

// crf[m][a][b] = em[m][b] + trans[a][b] ; em ld=128
__global__ __launch_bounds__(256)
void k_crf(const float* __restrict__ em, const float* __restrict__ trans,
           float* __restrict__ out){
  const int m = blockIdx.x;
  __shared__ float er[TAGSn];
  if (threadIdx.x < TAGSn) er[threadIdx.x] = em[(size_t)m*128 + threadIdx.x];
  __syncthreads();
  float* o = out + (size_t)m*2500;
  for (int r=threadIdx.x; r<2500; r+=256)
    o[r] = er[r % TAGSn] + trans[r];
}

// int tail outputs as floats
__global__ void k_tail(const int* __restrict__ tm, const int* __restrict__ ln,
                       const int* __restrict__ tc, float* __restrict__ out){
  const int i = blockIdx.x*256 + threadIdx.x;
  if (i < 8192)       out[i] = (float)tm[i];
  else if (i < 8256)  out[i] = (float)ln[i-8192];
  else if (i < 16448) out[i] = (float)tc[i-8256];
}

// ---------------------------------------------------------------------------
extern "C" void kernel_launch(void* const* d_in, const int* in_sizes, int n_in,
                              void* d_out, int out_size, void* d_ws, size_t ws_size,
                              hipStream_t stream){
  (void)in_sizes; (void)n_in; (void)out_size; (void)ws_size;
  const int*   wmap   = (const int*)d_in[0];
  const int*   cmapsf = (const int*)d_in[1];
  const int*   cmapsb = (const int*)d_in[2];
  const float* cmakf  = (const float*)d_in[3];
  const float* cmakb  = (const float*)d_in[4];
  const int*   tmaps  = (const int*)d_in[5];
  const int*   tmapc  = (const int*)d_in[6];
  const int*   lengths= (const int*)d_in[7];
  const float* ceW    = (const float*)d_in[8];
  const float* fcWih  = (const float*)d_in[9];
  const float* fcWhh  = (const float*)d_in[10];
  const float* fcb    = (const float*)d_in[11];
  const float* bcWih  = (const float*)d_in[12];
  const float* bcWhh  = (const float*)d_in[13];
  const float* bcb    = (const float*)d_in[14];
  const float* weW    = (const float*)d_in[15];
  const float* wfWih  = (const float*)d_in[16];
  const float* wfWhh  = (const float*)d_in[17];
  const float* wfb    = (const float*)d_in[18];
  const float* wbWih  = (const float*)d_in[19];
  const float* wbWhh  = (const float*)d_in[20];
  const float* wbb    = (const float*)d_in[21];
  const float* hwWt   = (const float*)d_in[22];
  const float* hwbt   = (const float*)d_in[23];
  const float* hwWg   = (const float*)d_in[24];
  const float* hwbg   = (const float*)d_in[25];
  const float* emW    = (const float*)d_in[26];
  const float* emb    = (const float*)d_in[27];
  const float* trans  = (const float*)d_in[28];

  // workspace layout (float units)
  float* p = (float*)d_ws;
  size_t o = 0;
  float* CWf  = p + o; o += 100*1024;
  float* CWb  = p + o; o += 100*1024;
  unsigned short* W8cf = (unsigned short*)(p + o); o += 65536;   // 1024*256 B
  unsigned short* W8cb = (unsigned short*)(p + o); o += 65536;
  unsigned short* W8wf = (unsigned short*)(p + o); o += 65536;
  unsigned short* W8wb = (unsigned short*)(p + o); o += 65536;
  unsigned short* Wp16f = (unsigned short*)(p + o); o += 1024*DWPn/2;  // bf16 1024x640
  unsigned short* Wp16b = (unsigned short*)(p + o); o += 1024*DWPn/2;
  unsigned short* hw16t = (unsigned short*)(p + o); o += 512*512/2;
  unsigned short* hw16g = (unsigned short*)(p + o); o += 512*512/2;
  unsigned short* em16W = (unsigned short*)(p + o); o += 128*512/2;
  float* embp = p + o; o += 128;
  int*   posf = (int*)(p + o); o += 64*512;
  int*   posb = (int*)(p + o); o += 64*512;
  unsigned short* sub16 = (unsigned short*)(p + o); o += (size_t)8192*512/2;  // also hout16
  float* hwz  = p + o; o += (size_t)8192*1024;                  // also wXf
  unsigned short* wq16 = (unsigned short*)(p + o); o += (size_t)8192*DWPn/2; // also em
  float* wXb  = p + o; o += (size_t)8192*1024;
  float* wXf  = hwz;
  unsigned short* hout16 = sub16;
  float* em   = (float*)wq16;

  float* out  = (float*)d_out;

  hipMemsetAsync(sub16, 0, (size_t)8192*512*2, stream);

  k_prep_cw <<<dim3(100,2), 256, 0, stream>>>(ceW, fcWih, fcb, bcWih, bcb, CWf, CWb);
  k_prep_w8 <<<dim3(512,4), 256, 0, stream>>>(fcWhh, bcWhh, wfWhh, wbWhh,
                                              W8cf, W8cb, W8wf, W8wb);
  k_pad16   <<<dim3(1024,2), 256, 0, stream>>>(wfWih, wbWih, Wp16f, Wp16b);
  k_w16     <<<dim3(512,2), 256, 0, stream>>>(hwWt, hwWg, hw16t, hw16g);
  k_em16    <<<128, 256, 0, stream>>>(emW, emb, em16W, embp);
  k_prep_pos<<<dim3(64,2), 64, 0, stream>>>(cmakf, cmakb, posf, posb);

  k_char_lstm<<<32, 1024, 0, stream>>>(cmapsf, cmapsb, CWf, CWb,
                                       (const unsigned char*)W8cf, (const unsigned char*)W8cb,
                                       posf, posb, sub16);

  // highway: hwz[:,0:512] = sub@Wt^T+bt ; hwz[:,512:1024] = sub@Wg^T+bg
  k_gemm16<<<dim3(64,4,2), 256, 0, stream>>>(sub16, 512, 512,
                                             hw16t, hw16g, 512,
                                             hwbt, hwbg,
                                             hwz, hwz+512, 1024);
  k_hwelt16<<<4096, 256, 0, stream>>>(hwz, sub16);

  k_wasm16<<<8192, 256, 0, stream>>>(wmap, weW, sub16, wq16);

  // word input projections: wX_d = w @ Wih_d^T + b_d
  k_gemm16<<<dim3(64,8,2), 256, 0, stream>>>(wq16, DWPn, DWPn,
                                             Wp16f, Wp16b, DWPn,
                                             wfb, wbb,
                                             wXf, wXb, 1024);

  k_word_lstm<<<64, 1024, 0, stream>>>(wXf, wXb,
                                       (const unsigned char*)W8wf, (const unsigned char*)W8wb,
                                       hout16);

  // em = hout @ emW^T + emb (padded to 128 tags), ld 128
  k_gemm16<<<dim3(64,1,1), 256, 0, stream>>>(hout16, 512, 512,
                                             em16W, em16W, 512,
                                             embp, embp,
                                             em, em, 128);

  k_crf<<<8192, 256, 0, stream>>>(em, trans, out);
  k_tail<<<65, 256, 0, stream>>>(tmaps, lengths, tmapc, out + (size_t)20480000);
}

// Round 13
// 672.050 us; speedup vs baseline: 3.1399x; 1.0307x over previous
//
#include <hip/hip_runtime.h>
#include <math.h>

#define Bn 64
#define Tn 128
#define TCn 512
#define CEn 64
#define CHn 256
#define TAGSn 50
#define DWPn 640   // word-LSTM input dim padded 612 -> 640

typedef float f32x4 __attribute__((ext_vector_type(4)));
typedef int   i32x4 __attribute__((ext_vector_type(4)));
typedef short bf16x8 __attribute__((ext_vector_type(8)));

#define DEQ 3.07578740157480315e-5f   // 1/(256*127)

__device__ __forceinline__ float sigf(float x){ return 1.0f/(1.0f+expf(-x)); }

__device__ __forceinline__ float fsig(float x){
  return __builtin_amdgcn_rcpf(1.f + exp2f(-1.4426950408889634f*x));
}
__device__ __forceinline__ float ftanh(float x){
  return 1.f - 2.f*__builtin_amdgcn_rcpf(1.f + exp2f(2.885390081777927f*x));
}

// barrier that drains only LDS (keeps global loads/stores in flight)
__device__ __forceinline__ void bar_lds(){
  asm volatile("s_waitcnt lgkmcnt(0)\n\ts_barrier" ::: "memory");
}

// f32 <-> bf16 (RNE)
__device__ __forceinline__ unsigned short f2bf(float x){
  unsigned u = __float_as_uint(x);
  u += 0x7fffu + ((u>>16)&1u);
  return (unsigned short)(u>>16);
}
__device__ __forceinline__ float bf2f(unsigned short h){
  return __uint_as_float(((unsigned)h)<<16);
}

// ---------------------------------------------------------------------------
// CW[d][c][u*4+k] = b_d[k*256+u] + sum_e ceW[c][e]*Wih_d[k*256+u][e]
__global__ void k_prep_cw(const float* __restrict__ ceW,
                          const float* __restrict__ Wf, const float* __restrict__ bf,
                          const float* __restrict__ Wb, const float* __restrict__ bb,
                          float* __restrict__ CWf, float* __restrict__ CWb){
  const int c = blockIdx.x, u = threadIdx.x;
  const float* Wih  = blockIdx.y ? Wb : Wf;
  const float* bias = blockIdx.y ? bb : bf;
  float*       CW   = blockIdx.y ? CWb : CWf;
  __shared__ float ce[CEn];
  if (u < CEn) ce[u] = ceW[c*CEn + u];
  __syncthreads();
  float a[4];
  #pragma unroll
  for (int k=0;k<4;k++){
    const float* wr = Wih + (size_t)(k*CHn+u)*CEn;
    float s = bias[k*CHn+u];
    #pragma unroll 4
    for (int e=0;e<CEn;e++) s += ce[e]*wr[e];
    a[k]=s;
  }
  ((float4*)CW)[c*CHn+u] = make_float4(a[0],a[1],a[2],a[3]);
}

// i8 Whh, gate-tile row permutation:
//   out row rp = wv*64 + nt*16 + m  <-  src row nt*256 + wv*16 + m
__global__ void k_prep_w8(const float* __restrict__ W0, const float* __restrict__ W1,
                          const float* __restrict__ W2, const float* __restrict__ W3,
                          unsigned short* __restrict__ O0, unsigned short* __restrict__ O1,
                          unsigned short* __restrict__ O2, unsigned short* __restrict__ O3){
  const int w = blockIdx.y;
  const float* W = (w==0)?W0:(w==1)?W1:(w==2)?W2:W3;
  unsigned short* O = (w==0)?O0:(w==1)?O1:(w==2)?O2:O3;
  const int i = blockIdx.x*256 + threadIdx.x;      // 131072 pairs
  const int rp = i >> 7;
  const int kp = (i & 127) * 2;
  const int sr = (((rp>>4)&3)*256) + ((rp>>6)*16) + (rp&15);
  const int b0 = (int)rintf(fminf(fmaxf(W[(size_t)sr*CHn + kp  ]*256.f,-127.f),127.f));
  const int b1 = (int)rintf(fminf(fmaxf(W[(size_t)sr*CHn + kp+1]*256.f,-127.f),127.f));
  O[(size_t)rp*128 + (kp>>1)] = (unsigned short)((b0 & 0xff) | ((b1 & 0xff) << 8));
}

// pad word Wih (1024,612) -> bf16 (1024,640)
__global__ void k_pad16(const float* __restrict__ Wf, const float* __restrict__ Wb,
                        unsigned short* __restrict__ Pf, unsigned short* __restrict__ Pb){
  const int j = blockIdx.x;
  const float* Win        = blockIdx.y ? Wb : Wf;
  unsigned short* Wout    = blockIdx.y ? Pb : Pf;
  for (int col=threadIdx.x; col<DWPn; col+=256)
    Wout[(size_t)j*DWPn+col] = (col<612) ? f2bf(Win[(size_t)j*612+col]) : 0;
}

// hwWt/hwWg (512,512) -> bf16
__global__ void k_w16(const float* __restrict__ Wt, const float* __restrict__ Wg,
                      unsigned short* __restrict__ Ot, unsigned short* __restrict__ Og){
  const int j = blockIdx.x;
  const float* W       = blockIdx.y ? Wg : Wt;
  unsigned short* O    = blockIdx.y ? Og : Ot;
  for (int col=threadIdx.x; col<512; col+=256)
    O[(size_t)j*512+col] = f2bf(W[(size_t)j*512+col]);
}

// emW (50,512) -> bf16 (128,512) padded; emb -> fp32 (128) padded
__global__ void k_em16(const float* __restrict__ emW, const float* __restrict__ emb,
                       unsigned short* __restrict__ Wp, float* __restrict__ bp){
  const int j = blockIdx.x;
  for (int col=threadIdx.x; col<512; col+=256)
    Wp[(size_t)j*512+col] = (j<TAGSn) ? f2bf(emW[(size_t)j*512+col]) : 0;
  if (threadIdx.x==0) bp[j] = (j<TAGSn) ? emb[j] : 0.f;
}

// stable-compaction ranks from cmakers only; grid (64,2), 64 threads (1 wave)
__global__ void k_prep_pos(const float* __restrict__ cmf, const float* __restrict__ cmb,
                           int* __restrict__ pf, int* __restrict__ pb){
  const float* cm = blockIdx.y ? cmb : cmf;
  int* pos        = blockIdx.y ? pb : pf;
  const int n = blockIdx.x, lane = threadIdx.x;
  int base = 0;
  for (int c=0;c<TCn/64;c++){
    int t = c*64 + lane;
    bool m = cm[n*TCn+t] != 0.f;
    unsigned long long bal = __ballot(m);
    int before = __popcll(bal & ((1ULL<<lane)-1ULL));
    int r = base + before;
    pos[n*TCn+t] = (m && r < Tn) ? r : -1;
    base += __popcll(bal);
  }
}

// ---------------------------------------------------------------------------
// char LSTM via i8 MFMA, gates in-register, 1 barrier/step, unroll-2,
// precomputed LDS addrs, DPP pack. 32 blocks, 1024 threads = 16 waves.
__global__ __launch_bounds__(1024, 4)
void k_char_lstm(const int* __restrict__ cmf, const int* __restrict__ cmb,
                 const float* __restrict__ CWf, const float* __restrict__ CWb,
                 const unsigned char* __restrict__ W8f, const unsigned char* __restrict__ W8b,
                 const int* __restrict__ posf, const int* __restrict__ posb,
                 unsigned short* __restrict__ sub16){
  const int dir = blockIdx.x >> 4, mg = blockIdx.x & 15;
  const int n0 = mg*4;
  const int t1 = threadIdx.x;
  const int wv = t1 >> 6, lane = t1 & 63;
  const int m = lane & 15, g = lane >> 4;
  const int*    cm  = dir ? cmb : cmf;
  const float4* CW  = (const float4*)(dir ? CWb : CWf);
  const unsigned char* W8 = dir ? W8b : W8f;
  const int*    pos = dir ? posb : posf;
  const int dofs = dir ? CHn : 0;

  __shared__ unsigned hbw[2][16][64];   // i8 h, 16B chunk idx XOR row; rows 4j = seq j

  i32x4 Bfr[4][4];
  #pragma unroll
  for (int nt=0;nt<4;nt++)
    #pragma unroll
    for (int kt=0;kt<4;kt++)
      Bfr[nt][kt] = *(const i32x4*)(W8 + (size_t)(wv*64 + nt*16 + m)*256 + kt*64 + g*16);

  for (int j=t1; j<2*16*64; j+=1024) ((unsigned*)hbw)[j] = 0u;
  const int uu = wv*16 + m;
  const int seq = n0 + g;
  const int* cmp  = cm  + seq*TCn;
  const int* posp = pos + seq*TCn;
  unsigned short* subp = sub16 + (size_t)seq*Tn*512 + dofs + uu;

  // precomputed LDS addresses (two parity sets)
  const int dwi = ((wv ^ (4*g)) << 2) | (m >> 2);
  unsigned* wp0 = &hbw[1][4*g][dwi];   // body par=0 writes buf 1
  unsigned* wp1 = &hbw[0][4*g][dwi];
  const i32x4* rp0[4]; const i32x4* rp1[4];
  {
    const char* r0 = (const char*)&hbw[0][0][0] + m*256;
    const char* r1 = (const char*)&hbw[1][0][0] + m*256;
    #pragma unroll
    for (int kt=0;kt<4;kt++){
      const int off = ((kt*4+g)^m)<<4;
      rp0[kt] = (const i32x4*)(r0 + off);
      rp1[kt] = (const i32x4*)(r1 + off);
    }
  }
  float cst = 0.f;
  __syncthreads();

  int    pp = posp[0];
  float4 cw = CW[(size_t)cmp[0]*CHn + uu];

#define CBODY(T, RP, WP) { \
    i32x4 a0 = *(RP)[0], a1 = *(RP)[1], a2 = *(RP)[2], a3 = *(RP)[3]; \
    const int tn_ = ((T)+1 < TCn) ? (T)+1 : (T); \
    const int ci2 = cmp[tn_]; \
    const int pp2 = posp[tn_]; \
    const float4 cw2 = CW[(size_t)ci2*CHn + uu]; \
    i32x4 c0={0,0,0,0}, c1={0,0,0,0}, c2={0,0,0,0}, c3={0,0,0,0}; \
    c0 = __builtin_amdgcn_mfma_i32_16x16x64_i8(a0, Bfr[0][0], c0, 0,0,0); \
    c1 = __builtin_amdgcn_mfma_i32_16x16x64_i8(a0, Bfr[1][0], c1, 0,0,0); \
    c2 = __builtin_amdgcn_mfma_i32_16x16x64_i8(a0, Bfr[2][0], c2, 0,0,0); \
    c3 = __builtin_amdgcn_mfma_i32_16x16x64_i8(a0, Bfr[3][0], c3, 0,0,0); \
    c0 = __builtin_amdgcn_mfma_i32_16x16x64_i8(a1, Bfr[0][1], c0, 0,0,0); \
    c1 = __builtin_amdgcn_mfma_i32_16x16x64_i8(a1, Bfr[1][1], c1, 0,0,0); \
    c2 = __builtin_amdgcn_mfma_i32_16x16x64_i8(a1, Bfr[2][1], c2, 0,0,0); \
    c3 = __builtin_amdgcn_mfma_i32_16x16x64_i8(a1, Bfr[3][1], c3, 0,0,0); \
    c0 = __builtin_amdgcn_mfma_i32_16x16x64_i8(a2, Bfr[0][2], c0, 0,0,0); \
    c1 = __builtin_amdgcn_mfma_i32_16x16x64_i8(a2, Bfr[1][2], c1, 0,0,0); \
    c2 = __builtin_amdgcn_mfma_i32_16x16x64_i8(a2, Bfr[2][2], c2, 0,0,0); \
    c3 = __builtin_amdgcn_mfma_i32_16x16x64_i8(a2, Bfr[3][2], c3, 0,0,0); \
    c0 = __builtin_amdgcn_mfma_i32_16x16x64_i8(a3, Bfr[0][3], c0, 0,0,0); \
    c1 = __builtin_amdgcn_mfma_i32_16x16x64_i8(a3, Bfr[1][3], c1, 0,0,0); \
    c2 = __builtin_amdgcn_mfma_i32_16x16x64_i8(a3, Bfr[2][3], c2, 0,0,0); \
    c3 = __builtin_amdgcn_mfma_i32_16x16x64_i8(a3, Bfr[3][3], c3, 0,0,0); \
    const float zi = fmaf((float)c0[0], DEQ, cw.x); \
    const float zf = fmaf((float)c1[0], DEQ, cw.y); \
    const float zg = fmaf((float)c2[0], DEQ, cw.z); \
    const float zo = fmaf((float)c3[0], DEQ, cw.w); \
    cst = fsig(zf)*cst + fsig(zi)*ftanh(zg); \
    const float hn = fsig(zo)*ftanh(cst); \
    int vv = ((int)rintf(hn*127.f)) & 0xff; \
    int tv = __builtin_amdgcn_mov_dpp(vv, 0xB1, 0xF, 0xF, true); \
    vv = (lane&1) ? ((vv<<8)|tv) : ((tv<<8)|vv); \
    tv = __builtin_amdgcn_mov_dpp(vv, 0x4E, 0xF, 0xF, true); \
    vv = (lane&2) ? ((vv<<16)|tv) : ((tv<<16)|vv); \
    if ((lane&3)==0) *(WP) = (unsigned)vv; \
    if (pp>=0) subp[(size_t)pp*512] = f2bf(hn); \
    bar_lds(); \
    pp = pp2; cw = cw2; }

  for (int t=0;t<TCn;t+=2){
    #pragma unroll
    for (int nt=0;nt<4;nt++)
      #pragma unroll
      for (int kt=0;kt<4;kt++)
        asm volatile("" : "+v"(Bfr[nt][kt]));
    CBODY(t,   rp0, wp0)
    CBODY(t+1, rp1, wp1)
  }
#undef CBODY
}

// ---------------------------------------------------------------------------
// word LSTM via i8 MFMA, same structure; writes bf16 hout. 64 blocks.
__global__ __launch_bounds__(1024, 4)
void k_word_lstm(const float* __restrict__ wXf, const float* __restrict__ wXb,
                 const unsigned char* __restrict__ W8f, const unsigned char* __restrict__ W8b,
                 unsigned short* __restrict__ hout16){
  const int dir = blockIdx.x >> 5, mg = blockIdx.x & 31;
  const int t0r = mg*4;
  const int t1 = threadIdx.x;
  const int wv = t1 >> 6, lane = t1 & 63;
  const int m = lane & 15, g = lane >> 4;
  const float* wX = dir ? wXb : wXf;
  const unsigned char* W8 = dir ? W8b : W8f;
  const int dofs = dir ? CHn : 0;

  __shared__ unsigned hbw[2][16][64];

  i32x4 Bfr[4][4];
  #pragma unroll
  for (int nt=0;nt<4;nt++)
    #pragma unroll
    for (int kt=0;kt<4;kt++)
      Bfr[nt][kt] = *(const i32x4*)(W8 + (size_t)(wv*64 + nt*16 + m)*256 + kt*64 + g*16);

  for (int j=t1; j<2*16*64; j+=1024) ((unsigned*)hbw)[j] = 0u;
  const int uu = wv*16 + m;
  const int row = t0r + g;
  const float* xbase = wX + (size_t)row*1024 + uu;
  unsigned short* hop = hout16 + (size_t)row*512 + dofs + uu;

  const int dwi = ((wv ^ (4*g)) << 2) | (m >> 2);
  unsigned* wp0 = &hbw[1][4*g][dwi];
  unsigned* wp1 = &hbw[0][4*g][dwi];
  const i32x4* rp0[4]; const i32x4* rp1[4];
  {
    const char* r0 = (const char*)&hbw[0][0][0] + m*256;
    const char* r1 = (const char*)&hbw[1][0][0] + m*256;
    #pragma unroll
    for (int kt=0;kt<4;kt++){
      const int off = ((kt*4+g)^m)<<4;
      rp0[kt] = (const i32x4*)(r0 + off);
      rp1[kt] = (const i32x4*)(r1 + off);
    }
  }
  float cst = 0.f;
  __syncthreads();

  {
    const int n00 = dir ? 63 : 0;
    const float* xp0 = xbase + (size_t)n00*131072;
    float4 zin = make_float4(xp0[0], xp0[256], xp0[512], xp0[768]);

#define WBODY(S, RP, WP) { \
    i32x4 a0 = *(RP)[0], a1 = *(RP)[1], a2 = *(RP)[2], a3 = *(RP)[3]; \
    const int n = dir ? (63-(S)) : (S); \
    const int sn_ = ((S)+1 < 64) ? (S)+1 : (S); \
    const int n2 = dir ? (63-sn_) : sn_; \
    const float* xp2 = xbase + (size_t)n2*131072; \
    const float4 zin2 = make_float4(xp2[0], xp2[256], xp2[512], xp2[768]); \
    i32x4 c0={0,0,0,0}, c1={0,0,0,0}, c2={0,0,0,0}, c3={0,0,0,0}; \
    c0 = __builtin_amdgcn_mfma_i32_16x16x64_i8(a0, Bfr[0][0], c0, 0,0,0); \
    c1 = __builtin_amdgcn_mfma_i32_16x16x64_i8(a0, Bfr[1][0], c1, 0,0,0); \
    c2 = __builtin_amdgcn_mfma_i32_16x16x64_i8(a0, Bfr[2][0], c2, 0,0,0); \
    c3 = __builtin_amdgcn_mfma_i32_16x16x64_i8(a0, Bfr[3][0], c3, 0,0,0); \
    c0 = __builtin_amdgcn_mfma_i32_16x16x64_i8(a1, Bfr[0][1], c0, 0,0,0); \
    c1 = __builtin_amdgcn_mfma_i32_16x16x64_i8(a1, Bfr[1][1], c1, 0,0,0); \
    c2 = __builtin_amdgcn_mfma_i32_16x16x64_i8(a1, Bfr[2][1], c2, 0,0,0); \
    c3 = __builtin_amdgcn_mfma_i32_16x16x64_i8(a1, Bfr[3][1], c3, 0,0,0); \
    c0 = __builtin_amdgcn_mfma_i32_16x16x64_i8(a2, Bfr[0][2], c0, 0,0,0); \
    c1 = __builtin_amdgcn_mfma_i32_16x16x64_i8(a2, Bfr[1][2], c1, 0,0,0); \
    c2 = __builtin_amdgcn_mfma_i32_16x16x64_i8(a2, Bfr[2][2], c2, 0,0,0); \
    c3 = __builtin_amdgcn_mfma_i32_16x16x64_i8(a2, Bfr[3][2], c3, 0,0,0); \
    c0 = __builtin_amdgcn_mfma_i32_16x16x64_i8(a3, Bfr[0][3], c0, 0,0,0); \
    c1 = __builtin_amdgcn_mfma_i32_16x16x64_i8(a3, Bfr[1][3], c1, 0,0,0); \
    c2 = __builtin_amdgcn_mfma_i32_16x16x64_i8(a3, Bfr[2][3], c2, 0,0,0); \
    c3 = __builtin_amdgcn_mfma_i32_16x16x64_i8(a3, Bfr[3][3], c3, 0,0,0); \
    const float zi = fmaf((float)c0[0], DEQ, zin.x); \
    const float zf = fmaf((float)c1[0], DEQ, zin.y); \
    const float zg = fmaf((float)c2[0], DEQ, zin.z); \
    const float zo = fmaf((float)c3[0], DEQ, zin.w); \
    cst = fsig(zf)*cst + fsig(zi)*ftanh(zg); \
    const float hn = fsig(zo)*ftanh(cst); \
    int vv = ((int)rintf(hn*127.f)) & 0xff; \
    int tv = __builtin_amdgcn_mov_dpp(vv, 0xB1, 0xF, 0xF, true); \
    vv = (lane&1) ? ((vv<<8)|tv) : ((tv<<8)|vv); \
    tv = __builtin_amdgcn_mov_dpp(vv, 0x4E, 0xF, 0xF, true); \
    vv = (lane&2) ? ((vv<<16)|tv) : ((tv<<16)|vv); \
    if ((lane&3)==0) *(WP) = (unsigned)vv; \
    hop[(size_t)n*65536] = f2bf(hn); \
    bar_lds(); \
    zin = zin2; }

    for (int s=0;s<64;s+=2){
      #pragma unroll
      for (int nt=0;nt<4;nt++)
        #pragma unroll
        for (int kt=0;kt<4;kt++)
          asm volatile("" : "+v"(Bfr[nt][kt]));
      WBODY(s,   rp0, wp0)
      WBODY(s+1, rp1, wp1)
    }
#undef WBODY
  }
}

// ---------------------------------------------------------------------------
// bf16 MFMA GEMM with register-staged double-buffer:
// C[m][n] = bias[n] + sum_k A[m][k]*W[n][k]; 128x128 tile, 256 thr, BK=32.
__global__ __launch_bounds__(256)
void k_gemm16(const unsigned short* __restrict__ A, int lda, int K,
              const unsigned short* __restrict__ W0, const unsigned short* __restrict__ W1, int ldw,
              const float* __restrict__ b0, const float* __restrict__ b1,
              float* __restrict__ C0, float* __restrict__ C1, int ldc){
  const unsigned short* W = blockIdx.z ? W1 : W0;
  const float* bias       = blockIdx.z ? b1 : b0;
  float*       C          = blockIdx.z ? C1 : C0;
  const int m0 = blockIdx.x*128, n0 = blockIdx.y*128;
  const int tid = threadIdx.x;
  const int wid = tid >> 6, l = tid & 63;
  const int wr = wid >> 1, wc = wid & 1;
  const int lm = l & 15, lk = l >> 4;
  __shared__ unsigned short As[128][40];
  __shared__ unsigned short Bs[128][40];
  f32x4 acc[4][4];
  #pragma unroll
  for (int i=0;i<4;i++)
    #pragma unroll
    for (int j=0;j<4;j++){ acc[i][j][0]=0.f; acc[i][j][1]=0.f; acc[i][j][2]=0.f; acc[i][j][3]=0.f; }

  const int sr = tid >> 1, sh = (tid & 1) * 16;
  const unsigned short* Ap = A + (size_t)(m0+sr)*lda + sh;
  const unsigned short* Wp = W + (size_t)(n0+sr)*ldw + sh;
  uint4 ra0 = *(const uint4*)(Ap);
  uint4 ra1 = *(const uint4*)(Ap + 8);
  uint4 rb0 = *(const uint4*)(Wp);
  uint4 rb1 = *(const uint4*)(Wp + 8);

  for (int kc=0; kc<K; kc+=32){
    *(uint4*)&As[sr][sh]   = ra0;
    *(uint4*)&As[sr][sh+8] = ra1;
    *(uint4*)&Bs[sr][sh]   = rb0;
    *(uint4*)&Bs[sr][sh+8] = rb1;
    __syncthreads();
    if (kc + 32 < K){               // prefetch next chunk under the MFMAs
      ra0 = *(const uint4*)(Ap + kc + 32);
      ra1 = *(const uint4*)(Ap + kc + 40);
      rb0 = *(const uint4*)(Wp + kc + 32);
      rb1 = *(const uint4*)(Wp + kc + 40);
    }
    bf16x8 af[4], bfr[4];
    #pragma unroll
    for (int mt=0;mt<4;mt++) af[mt]  = *(const bf16x8*)&As[wr*64+mt*16+lm][lk*8];
    #pragma unroll
    for (int nt=0;nt<4;nt++) bfr[nt] = *(const bf16x8*)&Bs[wc*64+nt*16+lm][lk*8];
    #pragma unroll
    for (int mt=0;mt<4;mt++)
      #pragma unroll
      for (int nt=0;nt<4;nt++)
        acc[mt][nt] = __builtin_amdgcn_mfma_f32_16x16x32_bf16(af[mt], bfr[nt], acc[mt][nt], 0,0,0);
    __syncthreads();
  }
  #pragma unroll
  for (int nt=0;nt<4;nt++){
    const int col = n0 + wc*64 + nt*16 + lm;
    const float bv = bias[col];
    #pragma unroll
    for (int mt=0;mt<4;mt++){
      const int r0 = m0 + wr*64 + mt*16 + lk*4;
      #pragma unroll
      for (int rg=0;rg<4;rg++)
        C[(size_t)(r0+rg)*ldc + col] = acc[mt][nt][rg] + bv;
    }
  }
}

// ---------------------------------------------------------------------------
// fused highway: zt = sub@Wt^T+bt, zg = sub@Wg^T+bg computed together,
// epilogue writes sub16 = sig(zg)*relu(zt) + (1-sig(zg))*sub16.
// grid (64,4), 256 threads, K=512.
__global__ __launch_bounds__(256, 1)
void k_hwgemm(unsigned short* __restrict__ sub16,
              const unsigned short* __restrict__ Wt, const unsigned short* __restrict__ Wg,
              const float* __restrict__ bt, const float* __restrict__ bg){
  const int m0 = blockIdx.x*128, n0 = blockIdx.y*128;
  const int tid = threadIdx.x;
  const int wid = tid >> 6, l = tid & 63;
  const int wr = wid >> 1, wc = wid & 1;
  const int lm = l & 15, lk = l >> 4;
  __shared__ unsigned short As[128][40];
  __shared__ unsigned short Bt[128][40];
  __shared__ unsigned short Bg[128][40];
  f32x4 zt[4][4], zg[4][4];
  #pragma unroll
  for (int i=0;i<4;i++)
    #pragma unroll
    for (int j=0;j<4;j++){
      zt[i][j][0]=0.f; zt[i][j][1]=0.f; zt[i][j][2]=0.f; zt[i][j][3]=0.f;
      zg[i][j][0]=0.f; zg[i][j][1]=0.f; zg[i][j][2]=0.f; zg[i][j][3]=0.f;
    }

  const int sr = tid >> 1, sh = (tid & 1) * 16;
  const unsigned short* Ap = sub16 + (size_t)(m0+sr)*512 + sh;
  const unsigned short* Tp = Wt + (size_t)(n0+sr)*512 + sh;
  const unsigned short* Gp = Wg + (size_t)(n0+sr)*512 + sh;
  uint4 ra0 = *(const uint4*)(Ap);
  uint4 ra1 = *(const uint4*)(Ap + 8);
  uint4 rt0 = *(const uint4*)(Tp);
  uint4 rt1 = *(const uint4*)(Tp + 8);
  uint4 rg0 = *(const uint4*)(Gp);
  uint4 rg1 = *(const uint4*)(Gp + 8);

  for (int kc=0; kc<512; kc+=32){
    *(uint4*)&As[sr][sh]   = ra0;
    *(uint4*)&As[sr][sh+8] = ra1;
    *(uint4*)&Bt[sr][sh]   = rt0;
    *(uint4*)&Bt[sr][sh+8] = rt1;
    *(uint4*)&Bg[sr][sh]   = rg0;
    *(uint4*)&Bg[sr][sh+8] = rg1;
    __syncthreads();
    if (kc + 32 < 512){
      ra0 = *(const uint4*)(Ap + kc + 32);
      ra1 = *(const uint4*)(Ap + kc + 40);
      rt0 = *(const uint4*)(Tp + kc + 32);
      rt1 = *(const uint4*)(Tp + kc + 40);
      rg0 = *(const uint4*)(Gp + kc + 32);
      rg1 = *(const uint4*)(Gp + kc + 40);
    }
    bf16x8 af[4], bt_[4], bg_[4];
    #pragma unroll
    for (int mt=0;mt<4;mt++) af[mt]  = *(const bf16x8*)&As[wr*64+mt*16+lm][lk*8];
    #pragma unroll
    for (int nt=0;nt<4;nt++){
      bt_[nt] = *(const bf16x8*)&Bt[wc*64+nt*16+lm][lk*8];
      bg_[nt] = *(const bf16x8*)&Bg[wc*64+nt*16+lm][lk*8];
    }
    #pragma unroll
    for (int mt=0;mt<4;mt++)
      #pragma unroll
      for (int nt=0;nt<4;nt++){
        zt[mt][nt] = __builtin_amdgcn_mfma_f32_16x16x32_bf16(af[mt], bt_[nt], zt[mt][nt], 0,0,0);
        zg[mt][nt] = __builtin_amdgcn_mfma_f32_16x16x32_bf16(af[mt], bg_[nt], zg[mt][nt], 0,0,0);
      }
    __syncthreads();
  }
  #pragma unroll
  for (int nt=0;nt<4;nt++){
    const int col = n0 + wc*64 + nt*16 + lm;
    const float btv = bt[col], bgv = bg[col];
    #pragma unroll
    for (int mt=0;mt<4;mt++){
      const int r0 = m0 + wr*64 + mt*16 + lk*4;
      #pragma unroll
      for (int rg=0;rg<4;rg++){
        const int row = r0 + rg;
        unsigned short* sp = sub16 + (size_t)row*512 + col;
        const float zt_v = zt[mt][nt][rg] + btv;
        const float zg_v = zg[mt][nt][rg] + bgv;
        const float gg = sigf(zg_v);
        const float tr = fmaxf(zt_v, 0.f);
        *sp = f2bf(gg*tr + (1.f-gg)*bf2f(*sp));
      }
    }
  }
}

// assemble padded word input (bf16)
__global__ void k_wasm16(const int* __restrict__ wmap, const float* __restrict__ weW,
                         const unsigned short* __restrict__ sub16,
                         unsigned short* __restrict__ wq16){
  const int m = blockIdx.x;
  const int wi = wmap[m];
  for (int col=threadIdx.x; col<DWPn; col+=256){
    unsigned short v = 0;
    if (col < 100)      v = f2bf(weW[(size_t)wi*100 + col]);
    else if (col < 612) v = sub16[(size_t)m*512 + (col-100)];
    wq16[(size_t)m*DWPn + col] = v;
  }
}

// crf[m][a][b] = em[m][b] + trans[a][b] ; em ld=128 ; float4 writes
__global__ __launch_bounds__(256)
void k_crf(const float* __restrict__ em, const float* __restrict__ trans,
           float* __restrict__ out){
  const int m = blockIdx.x;
  __shared__ float er[TAGSn];
  if (threadIdx.x < TAGSn) er[threadIdx.x] = em[(size_t)m*128 + threadIdx.x];
  __syncthreads();
  float4* o4 = (float4*)(out + (size_t)m*2500);
  const float4* t4 = (const float4*)trans;
  for (int r4=threadIdx.x; r4<625; r4+=256){
    const float4 tv = t4[r4];
    const int r = r4*4;
    float4 ov;
    ov.x = er[(r  ) % TAGSn] + tv.x;
    ov.y = er[(r+1) % TAGSn] + tv.y;
    ov.z = er[(r+2) % TAGSn] + tv.z;
    ov.w = er[(r+3) % TAGSn] + tv.w;
    o4[r4] = ov;
  }
}

// int tail outputs as floats
__global__ void k_tail(const int* __restrict__ tm, const int* __restrict__ ln,
                       const int* __restrict__ tc, float* __restrict__ out){
  const int i = blockIdx.x*256 + threadIdx.x;
  if (i < 8192)       out[i] = (float)tm[i];
  else if (i < 8256)  out[i] = (float)ln[i-8192];
  else if (i < 16448) out[i] = (float)tc[i-8256];
}

// ---------------------------------------------------------------------------
extern "C" void kernel_launch(void* const* d_in, const int* in_sizes, int n_in,
                              void* d_out, int out_size, void* d_ws, size_t ws_size,
                              hipStream_t stream){
  (void)in_sizes; (void)n_in; (void)out_size; (void)ws_size;
  const int*   wmap   = (const int*)d_in[0];
  const int*   cmapsf = (const int*)d_in[1];
  const int*   cmapsb = (const int*)d_in[2];
  const float* cmakf  = (const float*)d_in[3];
  const float* cmakb  = (const float*)d_in[4];
  const int*   tmaps  = (const int*)d_in[5];
  const int*   tmapc  = (const int*)d_in[6];
  const int*   lengths= (const int*)d_in[7];
  const float* ceW    = (const float*)d_in[8];
  const float* fcWih  = (const float*)d_in[9];
  const float* fcWhh  = (const float*)d_in[10];
  const float* fcb    = (const float*)d_in[11];
  const float* bcWih  = (const float*)d_in[12];
  const float* bcWhh  = (const float*)d_in[13];
  const float* bcb    = (const float*)d_in[14];
  const float* weW    = (const float*)d_in[15];
  const float* wfWih  = (const float*)d_in[16];
  const float* wfWhh  = (const float*)d_in[17];
  const float* wfb    = (const float*)d_in[18];
  const float* wbWih  = (const float*)d_in[19];
  const float* wbWhh  = (const float*)d_in[20];
  const float* wbb    = (const float*)d_in[21];
  const float* hwWt   = (const float*)d_in[22];
  const float* hwbt   = (const float*)d_in[23];
  const float* hwWg   = (const float*)d_in[24];
  const float* hwbg   = (const float*)d_in[25];
  const float* emW    = (const float*)d_in[26];
  const float* emb    = (const float*)d_in[27];
  const float* trans  = (const float*)d_in[28];

  // workspace layout (float units)
  float* p = (float*)d_ws;
  size_t o = 0;
  float* CWf  = p + o; o += 100*1024;
  float* CWb  = p + o; o += 100*1024;
  unsigned short* W8cf = (unsigned short*)(p + o); o += 65536;   // 1024*256 B
  unsigned short* W8cb = (unsigned short*)(p + o); o += 65536;
  unsigned short* W8wf = (unsigned short*)(p + o); o += 65536;
  unsigned short* W8wb = (unsigned short*)(p + o); o += 65536;
  unsigned short* Wp16f = (unsigned short*)(p + o); o += 1024*DWPn/2;  // bf16 1024x640
  unsigned short* Wp16b = (unsigned short*)(p + o); o += 1024*DWPn/2;
  unsigned short* hw16t = (unsigned short*)(p + o); o += 512*512/2;
  unsigned short* hw16g = (unsigned short*)(p + o); o += 512*512/2;
  unsigned short* em16W = (unsigned short*)(p + o); o += 128*512/2;
  float* embp = p + o; o += 128;
  int*   posf = (int*)(p + o); o += 64*512;
  int*   posb = (int*)(p + o); o += 64*512;
  unsigned short* sub16 = (unsigned short*)(p + o); o += (size_t)8192*512/2;  // also hout16
  float* hwz  = p + o; o += (size_t)8192*1024;                  // also wXf
  unsigned short* wq16 = (unsigned short*)(p + o); o += (size_t)8192*DWPn/2; // also em
  float* wXb  = p + o; o += (size_t)8192*1024;
  float* wXf  = hwz;
  unsigned short* hout16 = sub16;
  float* em   = (float*)wq16;

  float* out  = (float*)d_out;

  hipMemsetAsync(sub16, 0, (size_t)8192*512*2, stream);

  k_prep_cw <<<dim3(100,2), 256, 0, stream>>>(ceW, fcWih, fcb, bcWih, bcb, CWf, CWb);
  k_prep_w8 <<<dim3(512,4), 256, 0, stream>>>(fcWhh, bcWhh, wfWhh, wbWhh,
                                              W8cf, W8cb, W8wf, W8wb);
  k_pad16   <<<dim3(1024,2), 256, 0, stream>>>(wfWih, wbWih, Wp16f, Wp16b);
  k_w16     <<<dim3(512,2), 256, 0, stream>>>(hwWt, hwWg, hw16t, hw16g);
  k_em16    <<<128, 256, 0, stream>>>(emW, emb, em16W, embp);
  k_prep_pos<<<dim3(64,2), 64, 0, stream>>>(cmakf, cmakb, posf, posb);

  k_char_lstm<<<32, 1024, 0, stream>>>(cmapsf, cmapsb, CWf, CWb,
                                       (const unsigned char*)W8cf, (const unsigned char*)W8cb,
                                       posf, posb, sub16);

  // fused highway (reads + rewrites sub16 in place)
  k_hwgemm<<<dim3(64,4), 256, 0, stream>>>(sub16, hw16t, hw16g, hwbt, hwbg);

  k_wasm16<<<8192, 256, 0, stream>>>(wmap, weW, sub16, wq16);

  // word input projections: wX_d = w @ Wih_d^T + b_d
  k_gemm16<<<dim3(64,8,2), 256, 0, stream>>>(wq16, DWPn, DWPn,
                                             Wp16f, Wp16b, DWPn,
                                             wfb, wbb,
                                             wXf, wXb, 1024);

  k_word_lstm<<<64, 1024, 0, stream>>>(wXf, wXb,
                                       (const unsigned char*)W8wf, (const unsigned char*)W8wb,
                                       hout16);

  // em = hout @ emW^T + emb (padded to 128 tags), ld 128
  k_gemm16<<<dim3(64,1,1), 256, 0, stream>>>(hout16, 512, 512,
                                             em16W, em16W, 512,
                                             embp, embp,
                                             em, em, 128);

  k_crf<<<8192, 256, 0, stream>>>(em, trans, out);
  k_tail<<<65, 256, 0, stream>>>(tmaps, lengths, tmapc, out + (size_t)20480000);
}